// Round 2
// baseline (930.766 us; speedup 1.0000x reference)
//
#include <hip/hip_runtime.h>
#include <stdint.h>

typedef unsigned short u16;
typedef float v4f __attribute__((ext_vector_type(4)));
typedef short v8s __attribute__((ext_vector_type(8)));

#define CC 256
#define NNN 4096

__device__ __forceinline__ u16 f2bf(float f) {
  union { float f; uint32_t u; } c; c.f = f;
  uint32_t u = c.u;
  return (u16)((u + 0x7fffu + ((u >> 16) & 1u)) >> 16);
}
__device__ __forceinline__ float bf2f(u16 h) {
  union { uint32_t u; float f; } c; c.u = ((uint32_t)h) << 16;
  return c.f;
}
__device__ __forceinline__ void async16(const void* g, void* l) {
  __builtin_amdgcn_global_load_lds(
      (const __attribute__((address_space(1))) uint32_t*)g,
      (__attribute__((address_space(3))) uint32_t*)l, 16, 0, 0);
}

// ---- W [256][256] fp32 -> Ws [256][512] bf16 (hi | lo), K(c)-fast ----
__global__ __launch_bounds__(256) void wsplit(const float* __restrict__ W,
                                              u16* __restrict__ Ws) {
  const int d = blockIdx.x, c = threadIdx.x;
  float w = W[d * 256 + c];
  u16 hi = f2bf(w);
  Ws[d * 512 + c] = hi;
  Ws[d * 512 + 256 + c] = f2bf(w - bf2f(hi));
}

// ---- per batch: in [C][N] fp32 -> Ts [N][512] bf16 (hi|lo over c),
//      and Cb [C][N] bf16 (hi, straight copy) ----
__global__ __launch_bounds__(256) void tsplit(const float* __restrict__ in,
                                              u16* __restrict__ Ts,
                                              u16* __restrict__ Cb) {
  __shared__ u16 th[64][65];
  __shared__ u16 tl[64][65];
  const int bb = blockIdx.z;
  const int n0 = blockIdx.x * 64;
  const int c0 = blockIdx.y * 64;
  const int tx = threadIdx.x & 63;
  const int ty = threadIdx.x >> 6;  // 0..3
  const float* ib = in + (size_t)bb * CC * NNN;
  u16* Tb = Ts + (size_t)bb * NNN * 512;
  u16* Cbb = Cb + (size_t)bb * CC * NNN;
#pragma unroll
  for (int k = 0; k < 16; k++) {
    int r = ty + k * 4;
    float v = ib[(size_t)(c0 + r) * NNN + n0 + tx];
    u16 hi = f2bf(v);
    u16 lo = f2bf(v - bf2f(hi));
    th[r][tx] = hi;
    tl[r][tx] = lo;
    Cbb[(size_t)(c0 + r) * NNN + n0 + tx] = hi;
  }
  __syncthreads();
#pragma unroll
  for (int k = 0; k < 16; k++) {
    int r = ty + k * 4;
    Tb[(size_t)(n0 + r) * 512 + c0 + tx] = th[tx][r];
    Tb[(size_t)(n0 + r) * 512 + 256 + c0 + tx] = tl[tx][r];
  }
}

// ---- TN GEMM, logical K=768 over [hi|lo] stored operands (pitch 512).
// A remap: kA = k & 511      -> blocks hi, lo, hi
// B remap: kB = k>=256?k-256:k -> blocks hi, hi, lo
// => sum = Ahi*Bhi + Alo*Bhi + Ahi*Blo  (full fp32-grade product)
// MODE 0: out = hi/lo bf16, pitch 512 (the a~ result). M=4096,N=256.
// MODE 1: out = S [n][m] fp32 + ST [m][n] fp32. M=N=4096.
union alignas(16) SMemU {
  struct { u16 A[128 * 32]; u16 B[128 * 32]; } st;
  float tb[4 * 16 * 65];
};

template <int MODE>
__global__ __launch_bounds__(256) void gemm_tn(
    const u16* __restrict__ A, long sAb, const u16* __restrict__ Bm, long sBb,
    u16* __restrict__ outb, long sOb, float* __restrict__ S,
    float* __restrict__ ST) {
  const int bz = blockIdx.z;
  const u16* Ab = A + (size_t)bz * sAb;
  const u16* Bb = Bm + (size_t)bz * sBb;
  const int m0 = blockIdx.x * 128;
  const int n0 = blockIdx.y * 128;
  const int tid = threadIdx.x;
  const int wave = tid >> 6;
  const int lane = tid & 63;
  const int q = lane >> 4;
  const int l = lane & 15;
  const int wm = (wave >> 1) * 64;
  const int wn = (wave & 1) * 64;
  const int srow = lane >> 2, sch = lane & 3;

  __shared__ SMemU sm;

  v4f zero = {0.f, 0.f, 0.f, 0.f};
  v4f acc[4][4];
#pragma unroll
  for (int i = 0; i < 4; i++)
#pragma unroll
    for (int j = 0; j < 4; j++) acc[i][j] = zero;

  for (int k0 = 0; k0 < 768; k0 += 32) {
    const int kA = k0 & 511;
    const int kB = (k0 >= 256) ? (k0 - 256) : k0;
    __syncthreads();
#pragma unroll
    for (int ii = 0; ii < 2; ii++) {
      int r = wave * 32 + ii * 16 + srow;
      async16(Ab + (size_t)(m0 + r) * 512 + kA + sch * 8,
              &sm.st.A[r * 32 + sch * 8]);
    }
#pragma unroll
    for (int ii = 0; ii < 2; ii++) {
      int r = wave * 32 + ii * 16 + srow;
      async16(Bb + (size_t)(n0 + r) * 512 + kB + sch * 8,
              &sm.st.B[r * 32 + sch * 8]);
    }
    __syncthreads();
    v8s af[4], bfr[4];
#pragma unroll
    for (int i = 0; i < 4; i++)
      af[i] = *(const v8s*)&sm.st.A[(wm + i * 16 + l) * 32 + q * 8];
#pragma unroll
    for (int j = 0; j < 4; j++)
      bfr[j] = *(const v8s*)&sm.st.B[(wn + j * 16 + l) * 32 + q * 8];
#pragma unroll
    for (int i = 0; i < 4; i++)
#pragma unroll
      for (int j = 0; j < 4; j++)
        acc[i][j] =
            __builtin_amdgcn_mfma_f32_16x16x32_bf16(af[i], bfr[j], acc[i][j], 0, 0, 0);
  }

  if (MODE == 0) {
    u16* ob = outb + (size_t)bz * sOb;
#pragma unroll
    for (int i = 0; i < 4; i++)
#pragma unroll
      for (int j = 0; j < 4; j++)
#pragma unroll
        for (int r = 0; r < 4; r++) {
          int row = m0 + wm + i * 16 + q * 4 + r;
          int col = n0 + wn + j * 16 + l;
          float v = acc[i][j][r];
          u16 hi = f2bf(v);
          ob[(size_t)row * 512 + col] = hi;
          ob[(size_t)row * 512 + 256 + col] = f2bf(v - bf2f(hi));
        }
  } else {
#pragma unroll
    for (int i = 0; i < 4; i++)
#pragma unroll
      for (int j = 0; j < 4; j++)
#pragma unroll
        for (int r = 0; r < 4; r++) {
          int row = m0 + wm + i * 16 + q * 4 + r;  // S row n
          int col = n0 + wn + j * 16 + l;          // S col m
          S[(size_t)row * NNN + col] = acc[i][j][r];
        }
    __syncthreads();  // all waves done with staging LDS
    float* tb = &sm.tb[wave * 16 * 65];
#pragma unroll
    for (int j = 0; j < 4; j++) {
#pragma unroll
      for (int i = 0; i < 4; i++)
#pragma unroll
        for (int r = 0; r < 4; r++)
          tb[l * 65 + i * 16 + q * 4 + r] = acc[i][j][r];
      __syncthreads();
#pragma unroll
      for (int r16 = 0; r16 < 16; r16++) {
        float v = tb[r16 * 65 + lane];
        int mg = n0 + wn + j * 16 + r16;  // ST row = S col m
        int ng = m0 + wm + lane;          // ST col = S row n
        ST[(size_t)mg * NNN + ng] = v;
      }
      __syncthreads();
    }
  }
}

// ---- per-row online logsumexp over 4096 fp32: M[row], L[row] ----
__global__ __launch_bounds__(256) void rowstats(const float* __restrict__ src,
                                                float* __restrict__ M,
                                                float* __restrict__ L) {
  const float* r = src + (size_t)blockIdx.x * NNN;
  const int t = threadIdx.x;
  float m = -3e38f, s = 0.f;
  const float4* r4 = (const float4*)r;
  for (int k = t; k < 1024; k += 256) {
    float4 v = r4[k];
    float vm = fmaxf(fmaxf(v.x, v.y), fmaxf(v.z, v.w));
    if (vm > m) { s *= __expf(m - vm); m = vm; }
    s += __expf(v.x - m) + __expf(v.y - m) + __expf(v.z - m) + __expf(v.w - m);
  }
#pragma unroll
  for (int off = 1; off < 64; off <<= 1) {
    float m2 = __shfl_xor(m, off);
    float s2 = __shfl_xor(s, off);
    float mn = fmaxf(m, m2);
    s = s * __expf(m - mn) + s2 * __expf(m2 - mn);
    m = mn;
  }
  __shared__ float ms[4], ss[4];
  if ((t & 63) == 0) { ms[t >> 6] = m; ss[t >> 6] = s; }
  __syncthreads();
  if (t == 0) {
    float M0 = ms[0], S0 = ss[0];
#pragma unroll
    for (int w = 1; w < 4; w++) {
      float mn = fmaxf(M0, ms[w]);
      S0 = S0 * __expf(M0 - mn) + ss[w] * __expf(ms[w] - mn);
      M0 = mn;
    }
    M[blockIdx.x] = M0;
    L[blockIdx.x] = S0;
  }
}

// ---- PV: Out[c][x] = (sum_k V[c][k] * exp(P[x][k]-M[x])) / L[x], fp32 out.
// blockIdx.y==0: V=aCb, P=ST, stats=col -> a_new.  ==1: V=bCb, P=S, row -> b_new.
__global__ __launch_bounds__(256) void pv_k(
    const u16* __restrict__ aV, const u16* __restrict__ bV,
    const float* __restrict__ S, const float* __restrict__ ST,
    const float* __restrict__ Mr, const float* __restrict__ Lr,
    const float* __restrict__ Mc, const float* __restrict__ Lc,
    float* __restrict__ outA, float* __restrict__ outB) {
  const int which = blockIdx.y;
  const int x0 = blockIdx.x * 64;
  const u16* Av = which == 0 ? aV : bV;
  const float* P = which == 0 ? ST : S;
  const float* Mst = which == 0 ? Mc : Mr;
  const float* Lst = which == 0 ? Lc : Lr;
  float* Out = which == 0 ? outA : outB;

  const int tid = threadIdx.x;
  const int wave = tid >> 6, lane = tid & 63, q = lane >> 4, l = lane & 15;
  const int srow = lane >> 2, sch = lane & 3;
  const int xl = tid >> 2, ch = tid & 3;

  __shared__ alignas(16) u16 sA[256 * 32];
  __shared__ alignas(16) u16 sB[64 * 40];  // pitch 40 shorts (bank-safe)

  v4f zero = {0.f, 0.f, 0.f, 0.f};
  v4f acc[4][4];
#pragma unroll
  for (int i = 0; i < 4; i++)
#pragma unroll
    for (int j = 0; j < 4; j++) acc[i][j] = zero;

  const float mx = Mst[x0 + xl];

  for (int k0 = 0; k0 < NNN; k0 += 32) {
    __syncthreads();
#pragma unroll
    for (int ii = 0; ii < 4; ii++) {
      int r = wave * 64 + ii * 16 + srow;
      async16(Av + (size_t)r * NNN + k0 + sch * 8, &sA[r * 32 + sch * 8]);
    }
    {
      const float* gp = P + (size_t)(x0 + xl) * NNN + k0 + ch * 8;
      float4 v0 = ((const float4*)gp)[0];
      float4 v1 = ((const float4*)gp)[1];
      v8s pk;
      pk[0] = (short)f2bf(__expf(v0.x - mx));
      pk[1] = (short)f2bf(__expf(v0.y - mx));
      pk[2] = (short)f2bf(__expf(v0.z - mx));
      pk[3] = (short)f2bf(__expf(v0.w - mx));
      pk[4] = (short)f2bf(__expf(v1.x - mx));
      pk[5] = (short)f2bf(__expf(v1.y - mx));
      pk[6] = (short)f2bf(__expf(v1.z - mx));
      pk[7] = (short)f2bf(__expf(v1.w - mx));
      *(v8s*)&sB[xl * 40 + ch * 8] = pk;
    }
    __syncthreads();
    v8s af[4], bfr[4];
#pragma unroll
    for (int i = 0; i < 4; i++)
      af[i] = *(const v8s*)&sA[(wave * 64 + i * 16 + l) * 32 + q * 8];
#pragma unroll
    for (int j = 0; j < 4; j++)
      bfr[j] = *(const v8s*)&sB[(j * 16 + l) * 40 + q * 8];
#pragma unroll
    for (int i = 0; i < 4; i++)
#pragma unroll
      for (int j = 0; j < 4; j++)
        acc[i][j] =
            __builtin_amdgcn_mfma_f32_16x16x32_bf16(af[i], bfr[j], acc[i][j], 0, 0, 0);
  }

  float linv[4];
#pragma unroll
  for (int j = 0; j < 4; j++) linv[j] = 1.0f / Lst[x0 + j * 16 + l];
#pragma unroll
  for (int i = 0; i < 4; i++)
#pragma unroll
    for (int j = 0; j < 4; j++)
#pragma unroll
      for (int r = 0; r < 4; r++) {
        int c = wave * 64 + i * 16 + q * 4 + r;
        int x = x0 + j * 16 + l;
        Out[(size_t)c * NNN + x] = acc[i][j][r] * linv[j];
      }
}

extern "C" void kernel_launch(void* const* d_in, const int* in_sizes, int n_in,
                              void* d_out, int out_size, void* d_ws,
                              size_t ws_size, hipStream_t stream) {
  const float* a = (const float*)d_in[0];
  const float* b = (const float*)d_in[1];
  const float* W = (const float*)d_in[2];
  float* out = (float*)d_out;

  char* ws = (char*)d_ws;
  u16* Ws = (u16*)(ws);                    // 256*512*2       = 262144
  u16* aTs = (u16*)(ws + 262144);          // 4*4096*512*2    = 16777216
  u16* bTs = (u16*)(ws + 17039360);        // 16777216
  u16* aCb = (u16*)(ws + 33816576);        // 4*256*4096*2    = 8388608
  u16* bCb = (u16*)(ws + 42205184);        // 8388608
  u16* ats = (u16*)(ws + 50593792);        // 16777216
  float* Mrow = (float*)(ws + 67371008);   // 4096 floats each
  float* Lrow = Mrow + 4096;
  float* Mcol = Lrow + 4096;
  float* Lcol = Mcol + 4096;
  float* Sbuf = (float*)(ws + 67633152);   // 4096*4096*4 = 67108864
  float* STbuf = Sbuf + (size_t)NNN * NNN; // 67108864  (total ~193 MB)

  wsplit<<<dim3(256), 256, 0, stream>>>(W, Ws);
  tsplit<<<dim3(64, 4, 4), 256, 0, stream>>>(a, aTs, aCb);
  tsplit<<<dim3(64, 4, 4), 256, 0, stream>>>(b, bTs, bCb);
  // a~[n][d] = sum_c a[c][n] * W[d][c], hi/lo output
  gemm_tn<0><<<dim3(32, 2, 4), 256, 0, stream>>>(
      aTs, (long)NNN * 512, Ws, 0, ats, (long)NNN * 512, nullptr, nullptr);

  for (int p = 0; p < 4; p++) {
    const u16* atp = ats + (size_t)p * NNN * 512;
    const u16* btp = bTs + (size_t)p * NNN * 512;
    gemm_tn<1><<<dim3(32, 32, 1), 256, 0, stream>>>(
        atp, 0, btp, 0, nullptr, 0, Sbuf, STbuf);
    rowstats<<<dim3(4096), 256, 0, stream>>>(Sbuf, Mrow, Lrow);
    rowstats<<<dim3(4096), 256, 0, stream>>>(STbuf, Mcol, Lcol);
    pv_k<<<dim3(64, 2, 1), 256, 0, stream>>>(
        aCb + (size_t)p * CC * NNN, bCb + (size_t)p * CC * NNN, Sbuf, STbuf,
        Mrow, Lrow, Mcol, Lcol, out + (size_t)p * CC * NNN,
        out + 4194304 + (size_t)p * CC * NNN);
  }
}

// Round 3
// 919.368 us; speedup vs baseline: 1.0124x; 1.0124x over previous
//
#include <hip/hip_runtime.h>
#include <stdint.h>

typedef unsigned short u16;
typedef float v4f __attribute__((ext_vector_type(4)));
typedef short v8s __attribute__((ext_vector_type(8)));

#define CC 256
#define NNN 4096

__device__ __forceinline__ u16 f2bf(float f) {
  union { float f; uint32_t u; } c; c.f = f;
  uint32_t u = c.u;
  return (u16)((u + 0x7fffu + ((u >> 16) & 1u)) >> 16);
}
__device__ __forceinline__ float bf2f(u16 h) {
  union { uint32_t u; float f; } c; c.u = ((uint32_t)h) << 16;
  return c.f;
}
__device__ __forceinline__ void async16(const void* g, void* l) {
  __builtin_amdgcn_global_load_lds(
      (const __attribute__((address_space(1))) uint32_t*)g,
      (__attribute__((address_space(3))) uint32_t*)l, 16, 0, 0);
}

// ---- W [256][256] fp32 -> Ws [256][512] bf16 (hi | lo), K(c)-fast ----
__global__ __launch_bounds__(256) void wsplit(const float* __restrict__ W,
                                              u16* __restrict__ Ws) {
  const int d = blockIdx.x, c = threadIdx.x;
  float w = W[d * 256 + c];
  u16 hi = f2bf(w);
  Ws[d * 512 + c] = hi;
  Ws[d * 512 + 256 + c] = f2bf(w - bf2f(hi));
}

// ---- per batch: in [C][N] fp32 -> Ts [N][512] bf16 (hi|lo over c),
//      and Cb [C][N] bf16 (hi, straight copy) ----
__global__ __launch_bounds__(256) void tsplit(const float* __restrict__ in,
                                              u16* __restrict__ Ts,
                                              u16* __restrict__ Cb) {
  __shared__ u16 th[64][65];
  __shared__ u16 tl[64][65];
  const int bb = blockIdx.z;
  const int n0 = blockIdx.x * 64;
  const int c0 = blockIdx.y * 64;
  const int tx = threadIdx.x & 63;
  const int ty = threadIdx.x >> 6;  // 0..3
  const float* ib = in + (size_t)bb * CC * NNN;
  u16* Tb = Ts + (size_t)bb * NNN * 512;
  u16* Cbb = Cb + (size_t)bb * CC * NNN;
#pragma unroll
  for (int k = 0; k < 16; k++) {
    int r = ty + k * 4;
    float v = ib[(size_t)(c0 + r) * NNN + n0 + tx];
    u16 hi = f2bf(v);
    u16 lo = f2bf(v - bf2f(hi));
    th[r][tx] = hi;
    tl[r][tx] = lo;
    Cbb[(size_t)(c0 + r) * NNN + n0 + tx] = hi;
  }
  __syncthreads();
#pragma unroll
  for (int k = 0; k < 16; k++) {
    int r = ty + k * 4;
    Tb[(size_t)(n0 + r) * 512 + c0 + tx] = th[tx][r];
    Tb[(size_t)(n0 + r) * 512 + 256 + c0 + tx] = tl[tx][r];
  }
}

// ---- TN GEMM, logical K=768 over [hi|lo] stored operands (pitch 512).
// A remap: kA = k & 511        -> blocks hi, lo, hi
// B remap: kB = k>=256?k-256:k -> blocks hi, hi, lo
// => sum = Ahi*Bhi + Alo*Bhi + Ahi*Blo
// MODE 0: out = hi/lo bf16, pitch 512 (a~). MODE 1: S [n][m] + ST [m][n] fp32.
union alignas(16) SMemU {
  struct { u16 A[128 * 32]; u16 B[128 * 32]; } st;
  float tb[4 * 16 * 65];
};

template <int MODE>
__global__ __launch_bounds__(256) void gemm_tn(
    const u16* __restrict__ A, long sAb, const u16* __restrict__ Bm, long sBb,
    u16* __restrict__ outb, long sOb, float* __restrict__ S,
    float* __restrict__ ST) {
  const int bz = blockIdx.z;
  const u16* Ab = A + (size_t)bz * sAb;
  const u16* Bb = Bm + (size_t)bz * sBb;
  const int m0 = blockIdx.x * 128;
  const int n0 = blockIdx.y * 128;
  const int tid = threadIdx.x;
  const int wave = tid >> 6;
  const int lane = tid & 63;
  const int q = lane >> 4;
  const int l = lane & 15;
  const int wm = (wave >> 1) * 64;
  const int wn = (wave & 1) * 64;
  const int srow = lane >> 2, sch = lane & 3;

  __shared__ SMemU sm;

  v4f zero = {0.f, 0.f, 0.f, 0.f};
  v4f acc[4][4];
#pragma unroll
  for (int i = 0; i < 4; i++)
#pragma unroll
    for (int j = 0; j < 4; j++) acc[i][j] = zero;

  for (int k0 = 0; k0 < 768; k0 += 32) {
    const int kA = k0 & 511;
    const int kB = (k0 >= 256) ? (k0 - 256) : k0;
    __syncthreads();
#pragma unroll
    for (int ii = 0; ii < 2; ii++) {
      int r = wave * 32 + ii * 16 + srow;
      async16(Ab + (size_t)(m0 + r) * 512 + kA + sch * 8,
              &sm.st.A[r * 32 + sch * 8]);
    }
#pragma unroll
    for (int ii = 0; ii < 2; ii++) {
      int r = wave * 32 + ii * 16 + srow;
      async16(Bb + (size_t)(n0 + r) * 512 + kB + sch * 8,
              &sm.st.B[r * 32 + sch * 8]);
    }
    __syncthreads();
    v8s af[4], bfr[4];
#pragma unroll
    for (int i = 0; i < 4; i++)
      af[i] = *(const v8s*)&sm.st.A[(wm + i * 16 + l) * 32 + q * 8];
#pragma unroll
    for (int j = 0; j < 4; j++)
      bfr[j] = *(const v8s*)&sm.st.B[(wn + j * 16 + l) * 32 + q * 8];
#pragma unroll
    for (int i = 0; i < 4; i++)
#pragma unroll
      for (int j = 0; j < 4; j++)
        acc[i][j] =
            __builtin_amdgcn_mfma_f32_16x16x32_bf16(af[i], bfr[j], acc[i][j], 0, 0, 0);
  }

  if (MODE == 0) {
    u16* ob = outb + (size_t)bz * sOb;
#pragma unroll
    for (int i = 0; i < 4; i++)
#pragma unroll
      for (int j = 0; j < 4; j++)
#pragma unroll
        for (int r = 0; r < 4; r++) {
          int row = m0 + wm + i * 16 + q * 4 + r;
          int col = n0 + wn + j * 16 + l;
          float v = acc[i][j][r];
          u16 hi = f2bf(v);
          ob[(size_t)row * 512 + col] = hi;
          ob[(size_t)row * 512 + 256 + col] = f2bf(v - bf2f(hi));
        }
  } else {
    float* Sb = S + (size_t)bz * sOb;   // sOb = per-z S stride (elements)
    float* STb = ST + (size_t)bz * sOb;
#pragma unroll
    for (int i = 0; i < 4; i++)
#pragma unroll
      for (int j = 0; j < 4; j++)
#pragma unroll
        for (int r = 0; r < 4; r++) {
          int row = m0 + wm + i * 16 + q * 4 + r;  // S row n
          int col = n0 + wn + j * 16 + l;          // S col m
          Sb[(size_t)row * NNN + col] = acc[i][j][r];
        }
    __syncthreads();
    float* tb = &sm.tb[wave * 16 * 65];
#pragma unroll
    for (int j = 0; j < 4; j++) {
#pragma unroll
      for (int i = 0; i < 4; i++)
#pragma unroll
        for (int r = 0; r < 4; r++)
          tb[l * 65 + i * 16 + q * 4 + r] = acc[i][j][r];
      __syncthreads();
#pragma unroll
      for (int r16 = 0; r16 < 16; r16++) {
        float v = tb[r16 * 65 + lane];
        int mg = n0 + wn + j * 16 + r16;  // ST row = S col m
        int ng = m0 + wm + lane;          // ST col = S row n
        STb[(size_t)mg * NNN + ng] = v;
      }
      __syncthreads();
    }
  }
}

// ---- per-row online logsumexp over 4096 fp32. y=0: S->Mrow/Lrow, y=1: ST->Mcol/Lcol
__global__ __launch_bounds__(256) void rowstats2(
    const float* __restrict__ S, const float* __restrict__ ST, long sS,
    float* __restrict__ Mr, float* __restrict__ Lr, float* __restrict__ Mc,
    float* __restrict__ Lc) {
  const int z = blockIdx.z;
  const float* r = (blockIdx.y ? ST : S) + (size_t)z * sS +
                   (size_t)blockIdx.x * NNN;
  float* M = (blockIdx.y ? Mc : Mr) + (size_t)z * 4096;
  float* L = (blockIdx.y ? Lc : Lr) + (size_t)z * 4096;
  const int t = threadIdx.x;
  float m = -3e38f, s = 0.f;
  const float4* r4 = (const float4*)r;
  for (int k = t; k < 1024; k += 256) {
    float4 v = r4[k];
    float vm = fmaxf(fmaxf(v.x, v.y), fmaxf(v.z, v.w));
    if (vm > m) { s *= __expf(m - vm); m = vm; }
    s += __expf(v.x - m) + __expf(v.y - m) + __expf(v.z - m) + __expf(v.w - m);
  }
#pragma unroll
  for (int off = 1; off < 64; off <<= 1) {
    float m2 = __shfl_xor(m, off);
    float s2 = __shfl_xor(s, off);
    float mn = fmaxf(m, m2);
    s = s * __expf(m - mn) + s2 * __expf(m2 - mn);
    m = mn;
  }
  __shared__ float ms[4], ss[4];
  if ((t & 63) == 0) { ms[t >> 6] = m; ss[t >> 6] = s; }
  __syncthreads();
  if (t == 0) {
    float M0 = ms[0], S0 = ss[0];
#pragma unroll
    for (int w = 1; w < 4; w++) {
      float mn = fmaxf(M0, ms[w]);
      S0 = S0 * __expf(M0 - mn) + ss[w] * __expf(ms[w] - mn);
      M0 = mn;
    }
    M[blockIdx.x] = M0;
    L[blockIdx.x] = S0;
  }
}

// ---- PV: Out[c][x] = (sum_k V[c][k] * exp(P[x][k]-M[x])) / L[x], fp32 out.
// Tile 64(c) x 128(x); 4 waves, each 64c x 32x (acc[4][2]).
// blockIdx.y = which*4 + ct.  which 0: V=aCb, P=ST, col stats -> a_new.
//                             which 1: V=bCb, P=S,  row stats -> b_new.
__global__ __launch_bounds__(256) void pv_k(
    const u16* __restrict__ aV, const u16* __restrict__ bV,
    const float* __restrict__ S, const float* __restrict__ ST, long sS,
    const float* __restrict__ Mr, const float* __restrict__ Lr,
    const float* __restrict__ Mc, const float* __restrict__ Lc,
    float* __restrict__ outA, float* __restrict__ outB, int p0) {
  const int z = blockIdx.z;
  const int batch = p0 + z;
  const int which = blockIdx.y >> 2;
  const int ct = blockIdx.y & 3;
  const int x0 = blockIdx.x * 128;
  const int c0 = ct * 64;
  const u16* Av = (which ? bV : aV) + (size_t)batch * (CC * NNN);
  const float* P = (which ? S : ST) + (size_t)z * sS;
  const float* Mst = (which ? Mr : Mc) + (size_t)z * 4096;
  const float* Lst = (which ? Lr : Lc) + (size_t)z * 4096;
  float* Out = (which ? outB : outA) + (size_t)batch * (CC * NNN);

  const int tid = threadIdx.x;
  const int wave = tid >> 6, lane = tid & 63, q = lane >> 4, l = lane & 15;
  const int wn = wave * 32;
  const int vr = tid >> 2, vch = tid & 3;    // V staging: 64 rows x 4 chunks
  const int xr = tid >> 1, xh = tid & 1;     // P staging: 128 rows x 2 halves

  __shared__ alignas(16) u16 sA[64 * 32];
  __shared__ alignas(16) u16 sB[128 * 40];

  v4f zero = {0.f, 0.f, 0.f, 0.f};
  v4f acc[4][2];
#pragma unroll
  for (int i = 0; i < 4; i++)
#pragma unroll
    for (int j = 0; j < 2; j++) acc[i][j] = zero;

  const float mx = Mst[x0 + xr];

  for (int k0 = 0; k0 < NNN; k0 += 32) {
    __syncthreads();
    async16(Av + (size_t)(c0 + vr) * NNN + k0 + vch * 8,
            &sA[vr * 32 + vch * 8]);
    {
      const float* gp = P + (size_t)(x0 + xr) * NNN + k0 + xh * 16;
      float4 v0 = ((const float4*)gp)[0];
      float4 v1 = ((const float4*)gp)[1];
      float4 v2 = ((const float4*)gp)[2];
      float4 v3 = ((const float4*)gp)[3];
      v8s p0v, p1v;
      p0v[0] = (short)f2bf(__expf(v0.x - mx));
      p0v[1] = (short)f2bf(__expf(v0.y - mx));
      p0v[2] = (short)f2bf(__expf(v0.z - mx));
      p0v[3] = (short)f2bf(__expf(v0.w - mx));
      p0v[4] = (short)f2bf(__expf(v1.x - mx));
      p0v[5] = (short)f2bf(__expf(v1.y - mx));
      p0v[6] = (short)f2bf(__expf(v1.z - mx));
      p0v[7] = (short)f2bf(__expf(v1.w - mx));
      p1v[0] = (short)f2bf(__expf(v2.x - mx));
      p1v[1] = (short)f2bf(__expf(v2.y - mx));
      p1v[2] = (short)f2bf(__expf(v2.z - mx));
      p1v[3] = (short)f2bf(__expf(v2.w - mx));
      p1v[4] = (short)f2bf(__expf(v3.x - mx));
      p1v[5] = (short)f2bf(__expf(v3.y - mx));
      p1v[6] = (short)f2bf(__expf(v3.z - mx));
      p1v[7] = (short)f2bf(__expf(v3.w - mx));
      *(v8s*)&sB[xr * 40 + xh * 16] = p0v;
      *(v8s*)&sB[xr * 40 + xh * 16 + 8] = p1v;
    }
    __syncthreads();
    v8s af[4], bfr[2];
#pragma unroll
    for (int i = 0; i < 4; i++)
      af[i] = *(const v8s*)&sA[(i * 16 + l) * 32 + q * 8];
#pragma unroll
    for (int j = 0; j < 2; j++)
      bfr[j] = *(const v8s*)&sB[(wn + j * 16 + l) * 40 + q * 8];
#pragma unroll
    for (int i = 0; i < 4; i++)
#pragma unroll
      for (int j = 0; j < 2; j++)
        acc[i][j] =
            __builtin_amdgcn_mfma_f32_16x16x32_bf16(af[i], bfr[j], acc[i][j], 0, 0, 0);
  }

  float linv[2];
#pragma unroll
  for (int j = 0; j < 2; j++) linv[j] = 1.0f / Lst[x0 + wn + j * 16 + l];
#pragma unroll
  for (int i = 0; i < 4; i++)
#pragma unroll
    for (int j = 0; j < 2; j++)
#pragma unroll
      for (int r = 0; r < 4; r++) {
        int c = c0 + i * 16 + q * 4 + r;
        int x = x0 + wn + j * 16 + l;
        Out[(size_t)c * NNN + x] = acc[i][j][r] * linv[j];
      }
}

extern "C" void kernel_launch(void* const* d_in, const int* in_sizes, int n_in,
                              void* d_out, int out_size, void* d_ws,
                              size_t ws_size, hipStream_t stream) {
  const float* a = (const float*)d_in[0];
  const float* b = (const float*)d_in[1];
  const float* W = (const float*)d_in[2];
  float* out = (float*)d_out;

  char* ws = (char*)d_ws;
  u16* Ws = (u16*)(ws);                    // 262144
  u16* aTs = (u16*)(ws + 262144);          // 16777216
  u16* bTs = (u16*)(ws + 17039360);        // 16777216
  u16* aCb = (u16*)(ws + 33816576);        // 8388608
  u16* bCb = (u16*)(ws + 42205184);        // 8388608
  u16* ats = (u16*)(ws + 50593792);        // 16777216
  float* Mrow = (float*)(ws + 67371008);   // [4][4096] each (65536 B)
  float* Lrow = Mrow + 4 * 4096;
  float* Mcol = Lrow + 4 * 4096;
  float* Lcol = Mcol + 4 * 4096;
  float* Sbuf = (float*)(ws + 67633152);
  const size_t SELEMS = (size_t)NNN * NNN;
  const size_t SB = SELEMS * 4;

  int np = 1;
  if (ws_size >= (size_t)67633152 + 8 * SB) np = 4;
  else if (ws_size >= (size_t)67633152 + 4 * SB) np = 2;
  float* STbuf = Sbuf + (size_t)np * SELEMS;

  wsplit<<<dim3(256), 256, 0, stream>>>(W, Ws);
  tsplit<<<dim3(64, 4, 4), 256, 0, stream>>>(a, aTs, aCb);
  tsplit<<<dim3(64, 4, 4), 256, 0, stream>>>(b, bTs, bCb);
  gemm_tn<0><<<dim3(32, 2, 4), 256, 0, stream>>>(
      aTs, (long)NNN * 512, Ws, 0, ats, (long)NNN * 512, nullptr, nullptr);

  for (int p = 0; p < 4; p += np) {
    const u16* atp = ats + (size_t)p * NNN * 512;
    const u16* btp = bTs + (size_t)p * NNN * 512;
    gemm_tn<1><<<dim3(32, 32, np), 256, 0, stream>>>(
        atp, (long)NNN * 512, btp, (long)NNN * 512, nullptr, (long)SELEMS,
        Sbuf, STbuf);
    rowstats2<<<dim3(4096, 2, np), 256, 0, stream>>>(
        Sbuf, STbuf, (long)SELEMS, Mrow, Lrow, Mcol, Lcol);
    pv_k<<<dim3(32, 8, np), 256, 0, stream>>>(
        aCb, bCb, Sbuf, STbuf, (long)SELEMS, Mrow, Lrow, Mcol, Lcol,
        out, out + 4194304, p);
  }
}

// Round 4
// 600.063 us; speedup vs baseline: 1.5511x; 1.5321x over previous
//
#include <hip/hip_runtime.h>
#include <stdint.h>

typedef unsigned short u16;
typedef float v4f __attribute__((ext_vector_type(4)));
typedef short v8s __attribute__((ext_vector_type(8)));

#define CC 256
#define NNN 4096

__device__ __forceinline__ u16 f2bf(float f) {
  union { float f; uint32_t u; } c; c.f = f;
  uint32_t u = c.u;
  return (u16)((u + 0x7fffu + ((u >> 16) & 1u)) >> 16);
}
__device__ __forceinline__ float bf2f(u16 h) {
  union { uint32_t u; float f; } c; c.u = ((uint32_t)h) << 16;
  return c.f;
}
__device__ __forceinline__ void async16(const void* g, void* l) {
  __builtin_amdgcn_global_load_lds(
      (const __attribute__((address_space(1))) uint32_t*)g,
      (__attribute__((address_space(3))) uint32_t*)l, 16, 0, 0);
}

// ---- W [256][256] fp32 -> Ws [256][512] bf16 (hi | lo), K(c)-fast ----
__global__ __launch_bounds__(256) void wsplit(const float* __restrict__ W,
                                              u16* __restrict__ Ws) {
  const int d = blockIdx.x, c = threadIdx.x;
  float w = W[d * 256 + c];
  u16 hi = f2bf(w);
  Ws[d * 512 + c] = hi;
  Ws[d * 512 + 256 + c] = f2bf(w - bf2f(hi));
}

// ---- per batch: in [C][N] fp32 -> Ts [N][512] bf16 (hi|lo over c),
//      and Cb [C][N] bf16 (hi, straight copy) ----
__global__ __launch_bounds__(256) void tsplit(const float* __restrict__ in,
                                              u16* __restrict__ Ts,
                                              u16* __restrict__ Cb) {
  __shared__ u16 th[64][65];
  __shared__ u16 tl[64][65];
  const int bb = blockIdx.z;
  const int n0 = blockIdx.x * 64;
  const int c0 = blockIdx.y * 64;
  const int tx = threadIdx.x & 63;
  const int ty = threadIdx.x >> 6;  // 0..3
  const float* ib = in + (size_t)bb * CC * NNN;
  u16* Tb = Ts + (size_t)bb * NNN * 512;
  u16* Cbb = Cb + (size_t)bb * CC * NNN;
#pragma unroll
  for (int k = 0; k < 16; k++) {
    int r = ty + k * 4;
    float v = ib[(size_t)(c0 + r) * NNN + n0 + tx];
    u16 hi = f2bf(v);
    u16 lo = f2bf(v - bf2f(hi));
    th[r][tx] = hi;
    tl[r][tx] = lo;
    Cbb[(size_t)(c0 + r) * NNN + n0 + tx] = hi;
  }
  __syncthreads();
#pragma unroll
  for (int k = 0; k < 16; k++) {
    int r = ty + k * 4;
    Tb[(size_t)(n0 + r) * 512 + c0 + tx] = th[tx][r];
    Tb[(size_t)(n0 + r) * 512 + 256 + c0 + tx] = tl[tx][r];
  }
}

// ---- TN GEMM, logical K=768 over [hi|lo] stored operands (pitch 512).
// A remap: kA = k & 511        -> blocks hi, lo, hi
// B remap: kB = k>=256?k-256:k -> blocks hi, hi, lo
// MODE 0: out = hi/lo bf16, pitch 512 (a~). MODE 1: S [n][m] + ST [m][n] fp32.
union alignas(16) SMemU {
  struct { u16 A[128 * 32]; u16 B[128 * 32]; } st;
  float tb[4 * 16 * 65];
};

template <int MODE>
__global__ __launch_bounds__(256) void gemm_tn(
    const u16* __restrict__ A, long sAb, const u16* __restrict__ Bm, long sBb,
    u16* __restrict__ outb, long sOb, float* __restrict__ S,
    float* __restrict__ ST) {
  const int bz = blockIdx.z;
  const u16* Ab = A + (size_t)bz * sAb;
  const u16* Bb = Bm + (size_t)bz * sBb;
  const int m0 = blockIdx.x * 128;
  const int n0 = blockIdx.y * 128;
  const int tid = threadIdx.x;
  const int wave = tid >> 6;
  const int lane = tid & 63;
  const int q = lane >> 4;
  const int l = lane & 15;
  const int wm = (wave >> 1) * 64;
  const int wn = (wave & 1) * 64;
  const int srow = lane >> 2, sch = lane & 3;

  __shared__ SMemU sm;

  v4f zero = {0.f, 0.f, 0.f, 0.f};
  v4f acc[4][4];
#pragma unroll
  for (int i = 0; i < 4; i++)
#pragma unroll
    for (int j = 0; j < 4; j++) acc[i][j] = zero;

  for (int k0 = 0; k0 < 768; k0 += 32) {
    const int kA = k0 & 511;
    const int kB = (k0 >= 256) ? (k0 - 256) : k0;
    __syncthreads();
#pragma unroll
    for (int ii = 0; ii < 2; ii++) {
      int r = wave * 32 + ii * 16 + srow;
      async16(Ab + (size_t)(m0 + r) * 512 + kA + sch * 8,
              &sm.st.A[r * 32 + sch * 8]);
    }
#pragma unroll
    for (int ii = 0; ii < 2; ii++) {
      int r = wave * 32 + ii * 16 + srow;
      async16(Bb + (size_t)(n0 + r) * 512 + kB + sch * 8,
              &sm.st.B[r * 32 + sch * 8]);
    }
    __syncthreads();
    v8s af[4], bfr[4];
#pragma unroll
    for (int i = 0; i < 4; i++)
      af[i] = *(const v8s*)&sm.st.A[(wm + i * 16 + l) * 32 + q * 8];
#pragma unroll
    for (int j = 0; j < 4; j++)
      bfr[j] = *(const v8s*)&sm.st.B[(wn + j * 16 + l) * 32 + q * 8];
#pragma unroll
    for (int i = 0; i < 4; i++)
#pragma unroll
      for (int j = 0; j < 4; j++)
        acc[i][j] =
            __builtin_amdgcn_mfma_f32_16x16x32_bf16(af[i], bfr[j], acc[i][j], 0, 0, 0);
  }

  if (MODE == 0) {
    u16* ob = outb + (size_t)bz * sOb;
#pragma unroll
    for (int i = 0; i < 4; i++)
#pragma unroll
      for (int j = 0; j < 4; j++)
#pragma unroll
        for (int r = 0; r < 4; r++) {
          int row = m0 + wm + i * 16 + q * 4 + r;
          int col = n0 + wn + j * 16 + l;
          float v = acc[i][j][r];
          u16 hi = f2bf(v);
          ob[(size_t)row * 512 + col] = hi;
          ob[(size_t)row * 512 + 256 + col] = f2bf(v - bf2f(hi));
        }
  } else {
#pragma unroll
    for (int i = 0; i < 4; i++)
#pragma unroll
      for (int j = 0; j < 4; j++)
#pragma unroll
        for (int r = 0; r < 4; r++) {
          int row = m0 + wm + i * 16 + q * 4 + r;  // S row n
          int col = n0 + wn + j * 16 + l;          // S col m
          S[(size_t)row * NNN + col] = acc[i][j][r];
        }
    __syncthreads();
    float* tb = &sm.tb[wave * 16 * 65];
#pragma unroll
    for (int j = 0; j < 4; j++) {
#pragma unroll
      for (int i = 0; i < 4; i++)
#pragma unroll
        for (int r = 0; r < 4; r++)
          tb[l * 65 + i * 16 + q * 4 + r] = acc[i][j][r];
      __syncthreads();
#pragma unroll
      for (int r16 = 0; r16 < 16; r16++) {
        float v = tb[r16 * 65 + lane];
        int mg = n0 + wn + j * 16 + r16;  // ST row = S col m
        int ng = m0 + wm + lane;          // ST col = S row n
        ST[(size_t)mg * NNN + ng] = v;
      }
      __syncthreads();
    }
  }
}

// ---- per-row online logsumexp. y=0: S->Mrow/Lrow, y=1: ST->Mcol/Lcol ----
__global__ __launch_bounds__(256) void rowstats2(
    const float* __restrict__ S, const float* __restrict__ ST,
    float* __restrict__ Mr, float* __restrict__ Lr, float* __restrict__ Mc,
    float* __restrict__ Lc) {
  const float* r = (blockIdx.y ? ST : S) + (size_t)blockIdx.x * NNN;
  float* M = (blockIdx.y ? Mc : Mr);
  float* L = (blockIdx.y ? Lc : Lr);
  const int t = threadIdx.x;
  float m = -3e38f, s = 0.f;
  const float4* r4 = (const float4*)r;
  for (int k = t; k < 1024; k += 256) {
    float4 v = r4[k];
    float vm = fmaxf(fmaxf(v.x, v.y), fmaxf(v.z, v.w));
    if (vm > m) { s *= __expf(m - vm); m = vm; }
    s += __expf(v.x - m) + __expf(v.y - m) + __expf(v.z - m) + __expf(v.w - m);
  }
#pragma unroll
  for (int off = 1; off < 64; off <<= 1) {
    float m2 = __shfl_xor(m, off);
    float s2 = __shfl_xor(s, off);
    float mn = fmaxf(m, m2);
    s = s * __expf(m - mn) + s2 * __expf(m2 - mn);
    m = mn;
  }
  __shared__ float ms[4], ss[4];
  if ((t & 63) == 0) { ms[t >> 6] = m; ss[t >> 6] = s; }
  __syncthreads();
  if (t == 0) {
    float M0 = ms[0], S0 = ss[0];
#pragma unroll
    for (int w = 1; w < 4; w++) {
      float mn = fmaxf(M0, ms[w]);
      S0 = S0 * __expf(M0 - mn) + ss[w] * __expf(ms[w] - mn);
      M0 = mn;
    }
    M[blockIdx.x] = M0;
    L[blockIdx.x] = S0;
  }
}

// ---- K-split PV partial: part[split][which][c][x] = sum_{k in chunk}
//      V[c][k]*exp(P[x][k]-M[x]).  Block = 256c x 64x, K-chunk 1024. ----
__global__ __launch_bounds__(256) void pv_part(
    const u16* __restrict__ aV, const u16* __restrict__ bV,
    const float* __restrict__ S, const float* __restrict__ ST,
    const float* __restrict__ Mr, const float* __restrict__ Mc,
    float* __restrict__ part, int batch) {
  const int which = blockIdx.y;
  const int split = blockIdx.z;
  const int x0 = blockIdx.x * 64;
  const u16* Av = (which ? bV : aV) + (size_t)batch * (CC * NNN);
  const float* P = which ? S : ST;
  const float* Mst = which ? Mr : Mc;
  float* Out = part + ((size_t)split * 2 + which) * (CC * NNN);

  const int tid = threadIdx.x;
  const int wave = tid >> 6, lane = tid & 63, q = lane >> 4, l = lane & 15;
  const int srow = lane >> 2, sch = lane & 3;
  const int xl = tid >> 2, ch = tid & 3;

  __shared__ alignas(16) u16 sA[256 * 32];
  __shared__ alignas(16) u16 sB[64 * 40];

  v4f zero = {0.f, 0.f, 0.f, 0.f};
  v4f acc[4][4];
#pragma unroll
  for (int i = 0; i < 4; i++)
#pragma unroll
    for (int j = 0; j < 4; j++) acc[i][j] = zero;

  const float mx = Mst[x0 + xl];
  const int kbeg = split * 1024;

  for (int k0 = kbeg; k0 < kbeg + 1024; k0 += 32) {
    __syncthreads();
#pragma unroll
    for (int ii = 0; ii < 4; ii++) {
      int r = wave * 64 + ii * 16 + srow;
      async16(Av + (size_t)r * NNN + k0 + sch * 8, &sA[r * 32 + sch * 8]);
    }
    {
      const float* gp = P + (size_t)(x0 + xl) * NNN + k0 + ch * 8;
      float4 v0 = ((const float4*)gp)[0];
      float4 v1 = ((const float4*)gp)[1];
      v8s pk;
      pk[0] = (short)f2bf(__expf(v0.x - mx));
      pk[1] = (short)f2bf(__expf(v0.y - mx));
      pk[2] = (short)f2bf(__expf(v0.z - mx));
      pk[3] = (short)f2bf(__expf(v0.w - mx));
      pk[4] = (short)f2bf(__expf(v1.x - mx));
      pk[5] = (short)f2bf(__expf(v1.y - mx));
      pk[6] = (short)f2bf(__expf(v1.z - mx));
      pk[7] = (short)f2bf(__expf(v1.w - mx));
      *(v8s*)&sB[xl * 40 + ch * 8] = pk;
    }
    __syncthreads();
    v8s af[4], bfr[4];
#pragma unroll
    for (int i = 0; i < 4; i++)
      af[i] = *(const v8s*)&sA[(wave * 64 + i * 16 + l) * 32 + q * 8];
#pragma unroll
    for (int j = 0; j < 4; j++)
      bfr[j] = *(const v8s*)&sB[(j * 16 + l) * 40 + q * 8];
#pragma unroll
    for (int i = 0; i < 4; i++)
#pragma unroll
      for (int j = 0; j < 4; j++)
        acc[i][j] =
            __builtin_amdgcn_mfma_f32_16x16x32_bf16(af[i], bfr[j], acc[i][j], 0, 0, 0);
  }

#pragma unroll
  for (int i = 0; i < 4; i++)
#pragma unroll
    for (int j = 0; j < 4; j++)
#pragma unroll
      for (int r = 0; r < 4; r++) {
        int c = wave * 64 + i * 16 + q * 4 + r;
        int x = x0 + j * 16 + l;
        Out[(size_t)c * NNN + x] = acc[i][j][r];
      }
}

// ---- reduce 4 K-split partials, apply 1/L, write output ----
__global__ __launch_bounds__(256) void pv_reduce(
    const float* __restrict__ part, const float* __restrict__ Lr,
    const float* __restrict__ Lc, float* __restrict__ outA,
    float* __restrict__ outB, int batch) {
  const int bi = blockIdx.x;  // 0..511
  const int which = bi >> 8;
  const int c = bi & 255;
  const float* Lst = which ? Lr : Lc;
  float* Out = (which ? outB : outA) + (size_t)batch * CC * NNN +
               (size_t)c * NNN;
  const float* p0 = part + (size_t)which * (CC * NNN) + (size_t)c * NNN;
  const size_t ps = 2 * (size_t)CC * NNN;
  const int t = threadIdx.x;
#pragma unroll
  for (int xi = 0; xi < 4; xi++) {
    int x = xi * 1024 + t * 4;
    float4 a0 = *(const float4*)(p0 + x);
    float4 a1 = *(const float4*)(p0 + ps + x);
    float4 a2 = *(const float4*)(p0 + 2 * ps + x);
    float4 a3 = *(const float4*)(p0 + 3 * ps + x);
    float4 l4 = *(const float4*)(Lst + x);
    float4 o;
    o.x = (a0.x + a1.x + a2.x + a3.x) / l4.x;
    o.y = (a0.y + a1.y + a2.y + a3.y) / l4.y;
    o.z = (a0.z + a1.z + a2.z + a3.z) / l4.z;
    o.w = (a0.w + a1.w + a2.w + a3.w) / l4.w;
    *(float4*)(Out + x) = o;
  }
}

// ---- fallback PV (round-3 style, used only if ws too small for partials) --
__global__ __launch_bounds__(256) void pv_k(
    const u16* __restrict__ aV, const u16* __restrict__ bV,
    const float* __restrict__ S, const float* __restrict__ ST,
    const float* __restrict__ Mr, const float* __restrict__ Lr,
    const float* __restrict__ Mc, const float* __restrict__ Lc,
    float* __restrict__ outA, float* __restrict__ outB, int batch) {
  const int which = blockIdx.y;
  const int x0 = blockIdx.x * 64;
  const u16* Av = (which ? bV : aV) + (size_t)batch * (CC * NNN);
  const float* P = which ? S : ST;
  const float* Mst = which ? Mr : Mc;
  const float* Lst = which ? Lr : Lc;
  float* Out = (which ? outB : outA) + (size_t)batch * (CC * NNN);

  const int tid = threadIdx.x;
  const int wave = tid >> 6, lane = tid & 63, q = lane >> 4, l = lane & 15;
  const int srow = lane >> 2, sch = lane & 3;
  const int xl = tid >> 2, ch = tid & 3;

  __shared__ alignas(16) u16 sA[256 * 32];
  __shared__ alignas(16) u16 sB[64 * 40];

  v4f zero = {0.f, 0.f, 0.f, 0.f};
  v4f acc[4][4];
#pragma unroll
  for (int i = 0; i < 4; i++)
#pragma unroll
    for (int j = 0; j < 4; j++) acc[i][j] = zero;

  const float mx = Mst[x0 + xl];

  for (int k0 = 0; k0 < NNN; k0 += 32) {
    __syncthreads();
#pragma unroll
    for (int ii = 0; ii < 4; ii++) {
      int r = wave * 64 + ii * 16 + srow;
      async16(Av + (size_t)r * NNN + k0 + sch * 8, &sA[r * 32 + sch * 8]);
    }
    {
      const float* gp = P + (size_t)(x0 + xl) * NNN + k0 + ch * 8;
      float4 v0 = ((const float4*)gp)[0];
      float4 v1 = ((const float4*)gp)[1];
      v8s pk;
      pk[0] = (short)f2bf(__expf(v0.x - mx));
      pk[1] = (short)f2bf(__expf(v0.y - mx));
      pk[2] = (short)f2bf(__expf(v0.z - mx));
      pk[3] = (short)f2bf(__expf(v0.w - mx));
      pk[4] = (short)f2bf(__expf(v1.x - mx));
      pk[5] = (short)f2bf(__expf(v1.y - mx));
      pk[6] = (short)f2bf(__expf(v1.z - mx));
      pk[7] = (short)f2bf(__expf(v1.w - mx));
      *(v8s*)&sB[xl * 40 + ch * 8] = pk;
    }
    __syncthreads();
    v8s af[4], bfr[4];
#pragma unroll
    for (int i = 0; i < 4; i++)
      af[i] = *(const v8s*)&sA[(wave * 64 + i * 16 + l) * 32 + q * 8];
#pragma unroll
    for (int j = 0; j < 4; j++)
      bfr[j] = *(const v8s*)&sB[(j * 16 + l) * 40 + q * 8];
#pragma unroll
    for (int i = 0; i < 4; i++)
#pragma unroll
      for (int j = 0; j < 4; j++)
        acc[i][j] =
            __builtin_amdgcn_mfma_f32_16x16x32_bf16(af[i], bfr[j], acc[i][j], 0, 0, 0);
  }

  float linv[4];
#pragma unroll
  for (int j = 0; j < 4; j++) linv[j] = 1.0f / Lst[x0 + j * 16 + l];
#pragma unroll
  for (int i = 0; i < 4; i++)
#pragma unroll
    for (int j = 0; j < 4; j++)
#pragma unroll
      for (int r = 0; r < 4; r++) {
        int c = wave * 64 + i * 16 + q * 4 + r;
        int x = x0 + j * 16 + l;
        Out[(size_t)c * NNN + x] = acc[i][j][r] * linv[j];
      }
}

extern "C" void kernel_launch(void* const* d_in, const int* in_sizes, int n_in,
                              void* d_out, int out_size, void* d_ws,
                              size_t ws_size, hipStream_t stream) {
  const float* a = (const float*)d_in[0];
  const float* b = (const float*)d_in[1];
  const float* W = (const float*)d_in[2];
  float* out = (float*)d_out;

  char* ws = (char*)d_ws;
  u16* Ws = (u16*)(ws);                    // 262144
  u16* aTs = (u16*)(ws + 262144);          // 16777216
  u16* bTs = (u16*)(ws + 17039360);        // 16777216
  u16* aCb = (u16*)(ws + 33816576);        // 8388608
  u16* bCb = (u16*)(ws + 42205184);        // 8388608
  u16* ats = (u16*)(ws + 50593792);        // 16777216
  float* Mrow = (float*)(ws + 67371008);   // 4096 floats each
  float* Lrow = Mrow + 4096;
  float* Mcol = Lrow + 4096;
  float* Lcol = Mcol + 4096;
  float* Sbuf = (float*)(ws + 67633152);   // 67108864
  const size_t SELEMS = (size_t)NNN * NNN;
  float* STbuf = Sbuf + SELEMS;            // 67108864 -> ends 201850880
  float* Ppart = (float*)(ws + 201850880); // 4*2*256*4096*4 = 33554432
  const bool ksplit = ws_size >= (size_t)201850880 + 33554432;

  wsplit<<<dim3(256), 256, 0, stream>>>(W, Ws);
  tsplit<<<dim3(64, 4, 4), 256, 0, stream>>>(a, aTs, aCb);
  tsplit<<<dim3(64, 4, 4), 256, 0, stream>>>(b, bTs, bCb);
  gemm_tn<0><<<dim3(32, 2, 4), 256, 0, stream>>>(
      aTs, (long)NNN * 512, Ws, 0, ats, (long)NNN * 512, nullptr, nullptr);

  for (int p = 0; p < 4; p++) {
    const u16* atp = ats + (size_t)p * NNN * 512;
    const u16* btp = bTs + (size_t)p * NNN * 512;
    gemm_tn<1><<<dim3(32, 32, 1), 256, 0, stream>>>(
        atp, 0, btp, 0, nullptr, 0, Sbuf, STbuf);
    rowstats2<<<dim3(4096, 2, 1), 256, 0, stream>>>(
        Sbuf, STbuf, Mrow, Lrow, Mcol, Lcol);
    if (ksplit) {
      pv_part<<<dim3(64, 2, 4), 256, 0, stream>>>(
          aCb, bCb, Sbuf, STbuf, Mrow, Mcol, Ppart, p);
      pv_reduce<<<dim3(512), 256, 0, stream>>>(
          Ppart, Lrow, Lcol, out, out + 4194304, p);
    } else {
      pv_k<<<dim3(64, 2, 1), 256, 0, stream>>>(
          aCb, bCb, Sbuf, STbuf, Mrow, Lrow, Mcol, Lcol,
          out, out + 4194304, p);
    }
  }
}

// Round 5
// 510.094 us; speedup vs baseline: 1.8247x; 1.1764x over previous
//
#include <hip/hip_runtime.h>
#include <stdint.h>

typedef unsigned short u16;
typedef unsigned int u32;
typedef float v4f __attribute__((ext_vector_type(4)));
typedef short v8s __attribute__((ext_vector_type(8)));

#define CC 256
#define NNN 4096

__device__ __forceinline__ u16 f2bf(float f) {
  union { float f; uint32_t u; } c; c.f = f;
  uint32_t u = c.u;
  return (u16)((u + 0x7fffu + ((u >> 16) & 1u)) >> 16);
}
__device__ __forceinline__ float bf2f(u16 h) {
  union { uint32_t u; float f; } c; c.u = ((uint32_t)h) << 16;
  return c.f;
}
// monotone float<->uint encoding for atomicMax on fp32
__device__ __forceinline__ u32 encf(float f) {
  u32 u = __float_as_uint(f);
  return (u >> 31) ? ~u : (u | 0x80000000u);
}
__device__ __forceinline__ float decf(u32 u) {
  return (u >> 31) ? __uint_as_float(u & 0x7fffffffu) : __uint_as_float(~u);
}
__device__ __forceinline__ void async16(const void* g, void* l) {
  __builtin_amdgcn_global_load_lds(
      (const __attribute__((address_space(1))) uint32_t*)g,
      (__attribute__((address_space(3))) uint32_t*)l, 16, 0, 0);
}

// ---- W [256][256] fp32 -> Ws [256][512] bf16 (hi | lo), K(c)-fast ----
__global__ __launch_bounds__(256) void wsplit(const float* __restrict__ W,
                                              u16* __restrict__ Ws) {
  const int d = blockIdx.x, c = threadIdx.x;
  float w = W[d * 256 + c];
  u16 hi = f2bf(w);
  Ws[d * 512 + c] = hi;
  Ws[d * 512 + 256 + c] = f2bf(w - bf2f(hi));
}

// ---- per batch: in [C][N] fp32 -> Ts [N][512] bf16 (hi|lo over c),
//      and Cb [C][N] bf16 (hi, straight copy) ----
__global__ __launch_bounds__(256) void tsplit(const float* __restrict__ in,
                                              u16* __restrict__ Ts,
                                              u16* __restrict__ Cb) {
  __shared__ u16 th[64][65];
  __shared__ u16 tl[64][65];
  const int bb = blockIdx.z;
  const int n0 = blockIdx.x * 64;
  const int c0 = blockIdx.y * 64;
  const int tx = threadIdx.x & 63;
  const int ty = threadIdx.x >> 6;  // 0..3
  const float* ib = in + (size_t)bb * CC * NNN;
  u16* Tb = Ts + (size_t)bb * NNN * 512;
  u16* Cbb = Cb + (size_t)bb * CC * NNN;
#pragma unroll
  for (int k = 0; k < 16; k++) {
    int r = ty + k * 4;
    float v = ib[(size_t)(c0 + r) * NNN + n0 + tx];
    u16 hi = f2bf(v);
    u16 lo = f2bf(v - bf2f(hi));
    th[r][tx] = hi;
    tl[r][tx] = lo;
    Cbb[(size_t)(c0 + r) * NNN + n0 + tx] = hi;
  }
  __syncthreads();
#pragma unroll
  for (int k = 0; k < 16; k++) {
    int r = ty + k * 4;
    Tb[(size_t)(n0 + r) * 512 + c0 + tx] = th[tx][r];
    Tb[(size_t)(n0 + r) * 512 + 256 + c0 + tx] = tl[tx][r];
  }
}

// ---- TN GEMM, logical K=768 over [hi|lo] stored operands (pitch 512).
// A remap: kA = k & 511        -> blocks hi, lo, hi
// B remap: kB = k>=256?k-256:k -> blocks hi, hi, lo
// MODE 0: out = hi/lo bf16, pitch 512 (a~).
// MODE 1: out = S [n][m] fp32 + row/col max via atomicMax on encoded uints.
template <int MODE>
__global__ __launch_bounds__(256) void gemm_tn(
    const u16* __restrict__ A, long sAb, const u16* __restrict__ Bm, long sBb,
    u16* __restrict__ outb, long sOb, float* __restrict__ S,
    u32* __restrict__ Mru, u32* __restrict__ Mcu) {
  const int bz = blockIdx.z;
  const u16* Ab = A + (size_t)bz * sAb;
  const u16* Bb = Bm + (size_t)bz * sBb;
  const int m0 = blockIdx.x * 128;
  const int n0 = blockIdx.y * 128;
  const int tid = threadIdx.x;
  const int wave = tid >> 6;
  const int lane = tid & 63;
  const int q = lane >> 4;
  const int l = lane & 15;
  const int wm = (wave >> 1) * 64;
  const int wn = (wave & 1) * 64;
  const int srow = lane >> 2, sch = lane & 3;

  __shared__ alignas(16) u16 sA[128 * 32];
  __shared__ alignas(16) u16 sB[128 * 32];

  v4f zero = {0.f, 0.f, 0.f, 0.f};
  v4f acc[4][4];
#pragma unroll
  for (int i = 0; i < 4; i++)
#pragma unroll
    for (int j = 0; j < 4; j++) acc[i][j] = zero;

  for (int k0 = 0; k0 < 768; k0 += 32) {
    const int kA = k0 & 511;
    const int kB = (k0 >= 256) ? (k0 - 256) : k0;
    __syncthreads();
#pragma unroll
    for (int ii = 0; ii < 2; ii++) {
      int r = wave * 32 + ii * 16 + srow;
      async16(Ab + (size_t)(m0 + r) * 512 + kA + sch * 8,
              &sA[r * 32 + sch * 8]);
    }
#pragma unroll
    for (int ii = 0; ii < 2; ii++) {
      int r = wave * 32 + ii * 16 + srow;
      async16(Bb + (size_t)(n0 + r) * 512 + kB + sch * 8,
              &sB[r * 32 + sch * 8]);
    }
    __syncthreads();
    v8s af[4], bfr[4];
#pragma unroll
    for (int i = 0; i < 4; i++)
      af[i] = *(const v8s*)&sA[(wm + i * 16 + l) * 32 + q * 8];
#pragma unroll
    for (int j = 0; j < 4; j++)
      bfr[j] = *(const v8s*)&sB[(wn + j * 16 + l) * 32 + q * 8];
#pragma unroll
    for (int i = 0; i < 4; i++)
#pragma unroll
      for (int j = 0; j < 4; j++)
        acc[i][j] =
            __builtin_amdgcn_mfma_f32_16x16x32_bf16(af[i], bfr[j], acc[i][j], 0, 0, 0);
  }

  if (MODE == 0) {
    u16* ob = outb + (size_t)bz * sOb;
#pragma unroll
    for (int i = 0; i < 4; i++)
#pragma unroll
      for (int j = 0; j < 4; j++)
#pragma unroll
        for (int r = 0; r < 4; r++) {
          int row = m0 + wm + i * 16 + q * 4 + r;
          int col = n0 + wn + j * 16 + l;
          float v = acc[i][j][r];
          u16 hi = f2bf(v);
          ob[(size_t)row * 512 + col] = hi;
          ob[(size_t)row * 512 + 256 + col] = f2bf(v - bf2f(hi));
        }
  } else {
#pragma unroll
    for (int i = 0; i < 4; i++)
#pragma unroll
      for (int j = 0; j < 4; j++)
#pragma unroll
        for (int r = 0; r < 4; r++) {
          int row = m0 + wm + i * 16 + q * 4 + r;  // S row n
          int col = n0 + wn + j * 16 + l;          // S col m
          S[(size_t)row * NNN + col] = acc[i][j][r];
        }
    // --- row max (over this block's 128 cols) ---
    float rm[4][4];
#pragma unroll
    for (int i = 0; i < 4; i++)
#pragma unroll
      for (int r = 0; r < 4; r++) {
        float v = fmaxf(fmaxf(acc[i][0][r], acc[i][1][r]),
                        fmaxf(acc[i][2][r], acc[i][3][r]));
        rm[i][r] = v;
      }
#pragma unroll
    for (int off = 1; off < 16; off <<= 1)
#pragma unroll
      for (int i = 0; i < 4; i++)
#pragma unroll
        for (int r = 0; r < 4; r++)
          rm[i][r] = fmaxf(rm[i][r], __shfl_xor(rm[i][r], off));
    if (l == 0) {
#pragma unroll
      for (int i = 0; i < 4; i++)
#pragma unroll
        for (int r = 0; r < 4; r++)
          atomicMax(&Mru[m0 + wm + i * 16 + q * 4 + r], encf(rm[i][r]));
    }
    // --- col max (over this block's 128 rows) ---
    float cm[4];
#pragma unroll
    for (int j = 0; j < 4; j++) {
      float v = -3e38f;
#pragma unroll
      for (int i = 0; i < 4; i++)
#pragma unroll
        for (int r = 0; r < 4; r++) v = fmaxf(v, acc[i][j][r]);
      cm[j] = v;
    }
#pragma unroll
    for (int off = 16; off < 64; off <<= 1)
#pragma unroll
      for (int j = 0; j < 4; j++) cm[j] = fmaxf(cm[j], __shfl_xor(cm[j], off));
    if (q == 0) {
#pragma unroll
      for (int j = 0; j < 4; j++)
        atomicMax(&Mcu[n0 + wn + j * 16 + l], encf(cm[j]));
    }
  }
}

// ---- K-split PV partial with fused L accumulation.
// part[split][which][c][x] = sum_{k in chunk} V[c][k]*exp(P[x][k]-M[x])
// Lp[split][which][x]      = sum_{k in chunk} exp(P[x][k]-M[x])
// which=0: x=m, k=n, P[x][k]=S[k][x] (column gather), M=Mcu -> a_new
// which=1: x=n, k=m, P[x][k]=S[x][k] (row read),      M=Mru -> b_new
__global__ __launch_bounds__(256) void pv_part(
    const u16* __restrict__ aV, const u16* __restrict__ bV,
    const float* __restrict__ S, const u32* __restrict__ Mru,
    const u32* __restrict__ Mcu, float* __restrict__ part,
    float* __restrict__ Lp, int batch) {
  const int which = blockIdx.y;
  const int split = blockIdx.z;
  const int x0 = blockIdx.x * 64;
  const u16* Av = (which ? bV : aV) + (size_t)batch * (CC * NNN);
  const u32* Mst = which ? Mru : Mcu;
  float* Out = part + ((size_t)split * 2 + which) * (CC * NNN);
  float* Lpo = Lp + ((size_t)split * 2 + which) * NNN;

  const int tid = threadIdx.x;
  const int wave = tid >> 6, lane = tid & 63, q = lane >> 4, l = lane & 15;
  const int srow = lane >> 2, sch = lane & 3;
  // which=1 staging coords: 64 x-rows x 4 chunks of 8 k
  const int xl = tid >> 2, ch = tid & 3;
  // which=0 staging coords: 64 x-cols x 4 chunks of 8 k-rows
  const int xs = tid & 63, kq = (tid >> 6) * 8;

  __shared__ alignas(16) u16 sA[256 * 32];
  __shared__ alignas(16) u16 sB[64 * 40];
  __shared__ float lsh[256];

  v4f zero = {0.f, 0.f, 0.f, 0.f};
  v4f acc[4][4];
#pragma unroll
  for (int i = 0; i < 4; i++)
#pragma unroll
    for (int j = 0; j < 4; j++) acc[i][j] = zero;

  const float mx = decf(Mst[x0 + (which ? xl : xs)]);
  float lsum = 0.f;
  const int kbeg = split * 1024;

  for (int k0 = kbeg; k0 < kbeg + 1024; k0 += 32) {
    __syncthreads();
#pragma unroll
    for (int ii = 0; ii < 4; ii++) {
      int r = wave * 64 + ii * 16 + srow;
      async16(Av + (size_t)r * NNN + k0 + sch * 8, &sA[r * 32 + sch * 8]);
    }
    if (which) {
      const float* gp = S + (size_t)(x0 + xl) * NNN + k0 + ch * 8;
      float4 v0 = ((const float4*)gp)[0];
      float4 v1 = ((const float4*)gp)[1];
      float e0 = __expf(v0.x - mx), e1 = __expf(v0.y - mx);
      float e2 = __expf(v0.z - mx), e3 = __expf(v0.w - mx);
      float e4 = __expf(v1.x - mx), e5 = __expf(v1.y - mx);
      float e6 = __expf(v1.z - mx), e7 = __expf(v1.w - mx);
      lsum += ((e0 + e1) + (e2 + e3)) + ((e4 + e5) + (e6 + e7));
      v8s pk;
      pk[0] = (short)f2bf(e0); pk[1] = (short)f2bf(e1);
      pk[2] = (short)f2bf(e2); pk[3] = (short)f2bf(e3);
      pk[4] = (short)f2bf(e4); pk[5] = (short)f2bf(e5);
      pk[6] = (short)f2bf(e6); pk[7] = (short)f2bf(e7);
      *(v8s*)&sB[xl * 40 + ch * 8] = pk;
    } else {
      const float* gp = S + (size_t)(k0 + kq) * NNN + x0 + xs;
      v8s pk;
      float es[8];
#pragma unroll
      for (int e = 0; e < 8; e++) {
        float s = gp[(size_t)e * NNN];
        float p = __expf(s - mx);
        es[e] = p;
        pk[e] = (short)f2bf(p);
      }
      lsum += ((es[0] + es[1]) + (es[2] + es[3])) +
              ((es[4] + es[5]) + (es[6] + es[7]));
      *(v8s*)&sB[xs * 40 + kq] = pk;
    }
    __syncthreads();
    v8s af[4], bfr[4];
#pragma unroll
    for (int i = 0; i < 4; i++)
      af[i] = *(const v8s*)&sA[(wave * 64 + i * 16 + l) * 32 + q * 8];
#pragma unroll
    for (int j = 0; j < 4; j++)
      bfr[j] = *(const v8s*)&sB[(j * 16 + l) * 40 + q * 8];
#pragma unroll
    for (int i = 0; i < 4; i++)
#pragma unroll
      for (int j = 0; j < 4; j++)
        acc[i][j] =
            __builtin_amdgcn_mfma_f32_16x16x32_bf16(af[i], bfr[j], acc[i][j], 0, 0, 0);
  }

  // L partial reduction: 4 threads contribute per x
  __syncthreads();
  lsh[tid] = lsum;
  __syncthreads();
  if (tid < 64) {
    float t;
    if (which)
      t = (lsh[tid * 4] + lsh[tid * 4 + 1]) + (lsh[tid * 4 + 2] + lsh[tid * 4 + 3]);
    else
      t = (lsh[tid] + lsh[tid + 64]) + (lsh[tid + 128] + lsh[tid + 192]);
    Lpo[x0 + tid] = t;
  }

#pragma unroll
  for (int i = 0; i < 4; i++)
#pragma unroll
    for (int j = 0; j < 4; j++)
#pragma unroll
      for (int r = 0; r < 4; r++) {
        int c = wave * 64 + i * 16 + q * 4 + r;
        int x = x0 + j * 16 + l;
        Out[(size_t)c * NNN + x] = acc[i][j][r];
      }
}

// ---- reduce 4 K-split partials + L partials, apply 1/L, write output ----
__global__ __launch_bounds__(256) void pv_reduce(
    const float* __restrict__ part, const float* __restrict__ Lp,
    float* __restrict__ outA, float* __restrict__ outB, int batch) {
  const int bi = blockIdx.x;  // 0..511
  const int which = bi >> 8;
  const int c = bi & 255;
  float* Out = (which ? outB : outA) + (size_t)batch * CC * NNN +
               (size_t)c * NNN;
  const float* p0 = part + (size_t)which * (CC * NNN) + (size_t)c * NNN;
  const float* l0 = Lp + (size_t)which * NNN;
  const size_t ps = 2 * (size_t)CC * NNN;
  const size_t ls = 2 * (size_t)NNN;
  const int t = threadIdx.x;
#pragma unroll
  for (int xi = 0; xi < 4; xi++) {
    int x = xi * 1024 + t * 4;
    float4 a0 = *(const float4*)(p0 + x);
    float4 a1 = *(const float4*)(p0 + ps + x);
    float4 a2 = *(const float4*)(p0 + 2 * ps + x);
    float4 a3 = *(const float4*)(p0 + 3 * ps + x);
    float4 q0 = *(const float4*)(l0 + x);
    float4 q1 = *(const float4*)(l0 + ls + x);
    float4 q2 = *(const float4*)(l0 + 2 * ls + x);
    float4 q3 = *(const float4*)(l0 + 3 * ls + x);
    float4 o;
    o.x = ((a0.x + a1.x) + (a2.x + a3.x)) / ((q0.x + q1.x) + (q2.x + q3.x));
    o.y = ((a0.y + a1.y) + (a2.y + a3.y)) / ((q0.y + q1.y) + (q2.y + q3.y));
    o.z = ((a0.z + a1.z) + (a2.z + a3.z)) / ((q0.z + q1.z) + (q2.z + q3.z));
    o.w = ((a0.w + a1.w) + (a2.w + a3.w)) / ((q0.w + q1.w) + (q2.w + q3.w));
    *(float4*)(Out + x) = o;
  }
}

extern "C" void kernel_launch(void* const* d_in, const int* in_sizes, int n_in,
                              void* d_out, int out_size, void* d_ws,
                              size_t ws_size, hipStream_t stream) {
  const float* a = (const float*)d_in[0];
  const float* b = (const float*)d_in[1];
  const float* W = (const float*)d_in[2];
  float* out = (float*)d_out;

  char* ws = (char*)d_ws;
  u16* Ws = (u16*)(ws);                     // 262144
  u16* aTs = (u16*)(ws + 262144);           // 16777216
  u16* bTs = (u16*)(ws + 17039360);         // 16777216
  u16* aCb = (u16*)(ws + 33816576);         // 8388608
  u16* bCb = (u16*)(ws + 42205184);         // 8388608
  u16* ats = (u16*)(ws + 50593792);         // 16777216
  u32* Mru = (u32*)(ws + 67371008);         // 16384
  u32* Mcu = (u32*)(ws + 67387392);         // 16384
  float* Lp = (float*)(ws + 67403776);      // 4*2*4096*4 = 131072
  float* Sbuf = (float*)(ws + 67534848);    // 67108864
  float* Ppart = (float*)(ws + 134643712);  // 33554432 -> ends 168198144
  // ws >= 235 MB (proven by round-4 ksplit engaging); 168 MB needed.

  wsplit<<<dim3(256), 256, 0, stream>>>(W, Ws);
  tsplit<<<dim3(64, 4, 4), 256, 0, stream>>>(a, aTs, aCb);
  tsplit<<<dim3(64, 4, 4), 256, 0, stream>>>(b, bTs, bCb);
  gemm_tn<0><<<dim3(32, 2, 4), 256, 0, stream>>>(
      aTs, (long)NNN * 512, Ws, 0, ats, (long)NNN * 512, nullptr, nullptr,
      nullptr);

  for (int p = 0; p < 4; p++) {
    const u16* atp = ats + (size_t)p * NNN * 512;
    const u16* btp = bTs + (size_t)p * NNN * 512;
    hipMemsetAsync(Mru, 0, 32768, stream);  // Mru+Mcu contiguous
    gemm_tn<1><<<dim3(32, 32, 1), 256, 0, stream>>>(
        atp, 0, btp, 0, nullptr, 0, Sbuf, Mru, Mcu);
    pv_part<<<dim3(64, 2, 4), 256, 0, stream>>>(
        aCb, bCb, Sbuf, Mru, Mcu, Ppart, Lp, p);
    pv_reduce<<<dim3(512), 256, 0, stream>>>(
        Ppart, Lp, out, out + 4194304, p);
  }
}

// Round 6
// 461.284 us; speedup vs baseline: 2.0178x; 1.1058x over previous
//
#include <hip/hip_runtime.h>
#include <stdint.h>

typedef unsigned short u16;
typedef unsigned int u32;
typedef float v4f __attribute__((ext_vector_type(4)));
typedef short v8s __attribute__((ext_vector_type(8)));

#define CC 256
#define NNN 4096

__device__ __forceinline__ u16 f2bf(float f) {
  union { float f; uint32_t u; } c; c.f = f;
  uint32_t u = c.u;
  return (u16)((u + 0x7fffu + ((u >> 16) & 1u)) >> 16);
}
__device__ __forceinline__ float bf2f(u16 h) {
  union { uint32_t u; float f; } c; c.u = ((uint32_t)h) << 16;
  return c.f;
}
// monotone float<->uint encoding for atomicMax on fp32
__device__ __forceinline__ u32 encf(float f) {
  u32 u = __float_as_uint(f);
  return (u >> 31) ? ~u : (u | 0x80000000u);
}
__device__ __forceinline__ float decf(u32 u) {
  return (u >> 31) ? __uint_as_float(u & 0x7fffffffu) : __uint_as_float(~u);
}
__device__ __forceinline__ void async16(const void* g, void* l) {
  __builtin_amdgcn_global_load_lds(
      (const __attribute__((address_space(1))) uint32_t*)g,
      (__attribute__((address_space(3))) uint32_t*)l, 16, 0, 0);
}

// ---- W [256][256] fp32 -> Ws [256][512] bf16 (hi | lo), K(c)-fast ----
__global__ __launch_bounds__(256) void wsplit(const float* __restrict__ W,
                                              u16* __restrict__ Ws) {
  const int d = blockIdx.x, c = threadIdx.x;
  float w = W[d * 256 + c];
  u16 hi = f2bf(w);
  Ws[d * 512 + c] = hi;
  Ws[d * 512 + 256 + c] = f2bf(w - bf2f(hi));
}

// ---- per batch: in [C][N] fp32 -> Ts [N][512] bf16 (hi|lo over c),
//      and Cb [C][N] bf16 (hi, straight copy) ----
__global__ __launch_bounds__(256) void tsplit(const float* __restrict__ in,
                                              u16* __restrict__ Ts,
                                              u16* __restrict__ Cb) {
  __shared__ u16 th[64][65];
  __shared__ u16 tl[64][65];
  const int bb = blockIdx.z;
  const int n0 = blockIdx.x * 64;
  const int c0 = blockIdx.y * 64;
  const int tx = threadIdx.x & 63;
  const int ty = threadIdx.x >> 6;  // 0..3
  const float* ib = in + (size_t)bb * CC * NNN;
  u16* Tb = Ts + (size_t)bb * NNN * 512;
  u16* Cbb = Cb + (size_t)bb * CC * NNN;
#pragma unroll
  for (int k = 0; k < 16; k++) {
    int r = ty + k * 4;
    float v = ib[(size_t)(c0 + r) * NNN + n0 + tx];
    u16 hi = f2bf(v);
    u16 lo = f2bf(v - bf2f(hi));
    th[r][tx] = hi;
    tl[r][tx] = lo;
    Cbb[(size_t)(c0 + r) * NNN + n0 + tx] = hi;
  }
  __syncthreads();
#pragma unroll
  for (int k = 0; k < 16; k++) {
    int r = ty + k * 4;
    Tb[(size_t)(n0 + r) * 512 + c0 + tx] = th[tx][r];
    Tb[(size_t)(n0 + r) * 512 + 256 + c0 + tx] = tl[tx][r];
  }
}

// ---- TN GEMM, logical K=768 over [hi|lo] stored operands (pitch 512).
// BK=64, XOR-swizzled LDS: LDS[r][p] = global chunk p^(r&7) (8-short chunks).
// A remap: kA = k & 511        -> blocks hi, lo, hi
// B remap: kB = k>=256?k-256:k -> blocks hi, hi, lo
// MODE 0: out = hi/lo bf16, pitch 512 (a~).
// MODE 1: out = S [n][m] fp32 + row/col max via atomicMax on encoded uints.
template <int MODE>
__global__ __launch_bounds__(256) void gemm_tn(
    const u16* __restrict__ A, long sAb, const u16* __restrict__ Bm, long sBb,
    u16* __restrict__ outb, long sOb, float* __restrict__ S,
    u32* __restrict__ Mru, u32* __restrict__ Mcu) {
  const int bz = blockIdx.z;
  const u16* Ab = A + (size_t)bz * sAb;
  const u16* Bb = Bm + (size_t)bz * sBb;
  const int m0 = blockIdx.x * 128;
  const int n0 = blockIdx.y * 128;
  const int tid = threadIdx.x;
  const int wave = tid >> 6;
  const int lane = tid & 63;
  const int q = lane >> 4;
  const int l = lane & 15;
  const int l7 = l & 7;
  const int wm = (wave >> 1) * 64;
  const int wn = (wave & 1) * 64;
  // staging coords: 8 rows x 8 chunks per async16 wave-instruction
  const int sr = lane >> 3;           // row-in-group 0..7
  const int sp = lane & 7;            // LDS chunk position 0..7
  const int sg = sp ^ sr;             // global chunk index (swizzle)

  __shared__ alignas(16) u16 sA[128 * 64];
  __shared__ alignas(16) u16 sB[128 * 64];

  v4f zero = {0.f, 0.f, 0.f, 0.f};
  v4f acc[4][4];
#pragma unroll
  for (int i = 0; i < 4; i++)
#pragma unroll
    for (int j = 0; j < 4; j++) acc[i][j] = zero;

  for (int k0 = 0; k0 < 768; k0 += 64) {
    const int kA = k0 & 511;
    const int kB = (k0 >= 256) ? (k0 - 256) : k0;
    __syncthreads();
#pragma unroll
    for (int ii = 0; ii < 4; ii++) {
      int r = wave * 32 + ii * 8 + sr;
      async16(Ab + (size_t)(m0 + r) * 512 + kA + sg * 8,
              &sA[r * 64 + sp * 8]);
    }
#pragma unroll
    for (int ii = 0; ii < 4; ii++) {
      int r = wave * 32 + ii * 8 + sr;
      async16(Bb + (size_t)(n0 + r) * 512 + kB + sg * 8,
              &sB[r * 64 + sp * 8]);
    }
    __syncthreads();
#pragma unroll
    for (int s = 0; s < 2; s++) {
      const int pa = (s * 4 + q) ^ l7;  // LDS position of global chunk s*4+q
      v8s af[4], bfr[4];
#pragma unroll
      for (int i = 0; i < 4; i++)
        af[i] = *(const v8s*)&sA[(wm + i * 16 + l) * 64 + pa * 8];
#pragma unroll
      for (int j = 0; j < 4; j++)
        bfr[j] = *(const v8s*)&sB[(wn + j * 16 + l) * 64 + pa * 8];
#pragma unroll
      for (int i = 0; i < 4; i++)
#pragma unroll
        for (int j = 0; j < 4; j++)
          acc[i][j] = __builtin_amdgcn_mfma_f32_16x16x32_bf16(af[i], bfr[j],
                                                              acc[i][j], 0, 0, 0);
    }
  }

  if (MODE == 0) {
    u16* ob = outb + (size_t)bz * sOb;
#pragma unroll
    for (int i = 0; i < 4; i++)
#pragma unroll
      for (int j = 0; j < 4; j++)
#pragma unroll
        for (int r = 0; r < 4; r++) {
          int row = m0 + wm + i * 16 + q * 4 + r;
          int col = n0 + wn + j * 16 + l;
          float v = acc[i][j][r];
          u16 hi = f2bf(v);
          ob[(size_t)row * 512 + col] = hi;
          ob[(size_t)row * 512 + 256 + col] = f2bf(v - bf2f(hi));
        }
  } else {
#pragma unroll
    for (int i = 0; i < 4; i++)
#pragma unroll
      for (int j = 0; j < 4; j++)
#pragma unroll
        for (int r = 0; r < 4; r++) {
          int row = m0 + wm + i * 16 + q * 4 + r;  // S row n
          int col = n0 + wn + j * 16 + l;          // S col m
          S[(size_t)row * NNN + col] = acc[i][j][r];
        }
    // --- row max (over this block's 128 cols) ---
    float rm[4][4];
#pragma unroll
    for (int i = 0; i < 4; i++)
#pragma unroll
      for (int r = 0; r < 4; r++)
        rm[i][r] = fmaxf(fmaxf(acc[i][0][r], acc[i][1][r]),
                         fmaxf(acc[i][2][r], acc[i][3][r]));
#pragma unroll
    for (int off = 1; off < 16; off <<= 1)
#pragma unroll
      for (int i = 0; i < 4; i++)
#pragma unroll
        for (int r = 0; r < 4; r++)
          rm[i][r] = fmaxf(rm[i][r], __shfl_xor(rm[i][r], off));
    if (l == 0) {
#pragma unroll
      for (int i = 0; i < 4; i++)
#pragma unroll
        for (int r = 0; r < 4; r++)
          atomicMax(&Mru[m0 + wm + i * 16 + q * 4 + r], encf(rm[i][r]));
    }
    // --- col max (over this block's 128 rows) ---
    float cm[4];
#pragma unroll
    for (int j = 0; j < 4; j++) {
      float v = -3e38f;
#pragma unroll
      for (int i = 0; i < 4; i++)
#pragma unroll
        for (int r = 0; r < 4; r++) v = fmaxf(v, acc[i][j][r]);
      cm[j] = v;
    }
#pragma unroll
    for (int off = 16; off < 64; off <<= 1)
#pragma unroll
      for (int j = 0; j < 4; j++) cm[j] = fmaxf(cm[j], __shfl_xor(cm[j], off));
    if (q == 0) {
#pragma unroll
      for (int j = 0; j < 4; j++)
        atomicMax(&Mcu[n0 + wn + j * 16 + l], encf(cm[j]));
    }
  }
}

// ---- K-split PV partial with fused L accumulation. BK=64, swizzled LDS.
// part[split][which][c][x] = sum_{k in chunk} V[c][k]*exp(P[x][k]-M[x])
// Lp[split][which][x]      = sum_{k in chunk} exp(P[x][k]-M[x])
// which=0: x=m, k=n, P[x][k]=S[k][x] (column gather), M=Mcu -> a_new
// which=1: x=n, k=m, P[x][k]=S[x][k] (row read),      M=Mru -> b_new
__global__ __launch_bounds__(256) void pv_part(
    const u16* __restrict__ aV, const u16* __restrict__ bV,
    const float* __restrict__ S, const u32* __restrict__ Mru,
    const u32* __restrict__ Mcu, float* __restrict__ part,
    float* __restrict__ Lp, int batch) {
  const int which = blockIdx.y;
  const int split = blockIdx.z;
  const int x0 = blockIdx.x * 64;
  const u16* Av = (which ? bV : aV) + (size_t)batch * (CC * NNN);
  const u32* Mst = which ? Mru : Mcu;
  float* Out = part + ((size_t)split * 2 + which) * (CC * NNN);
  float* Lpo = Lp + ((size_t)split * 2 + which) * NNN;

  const int tid = threadIdx.x;
  const int wave = tid >> 6, lane = tid & 63, q = lane >> 4, l = lane & 15;
  const int l7 = l & 7;
  const int sr = lane >> 3, sp = lane & 7, sg = sp ^ sr;
  // which=1 S-read coords: 64 x-rows x 4 chunks of 16 k
  const int xl = tid >> 2, ch = tid & 3;
  // which=0 S-read coords: 64 x-cols x 4 groups of 16 k-rows
  const int xs = tid & 63, kq = (tid >> 6) * 16;

  __shared__ alignas(16) u16 sA[256 * 64];
  __shared__ alignas(16) u16 sB[64 * 64];
  __shared__ float lsh[256];

  v4f zero = {0.f, 0.f, 0.f, 0.f};
  v4f acc[4][4];
#pragma unroll
  for (int i = 0; i < 4; i++)
#pragma unroll
    for (int j = 0; j < 4; j++) acc[i][j] = zero;

  const float mx = decf(Mst[x0 + (which ? xl : xs)]);
  float lsum = 0.f;
  const int kbeg = split * 1024;

  for (int k0 = kbeg; k0 < kbeg + 1024; k0 += 64) {
    __syncthreads();
#pragma unroll
    for (int ii = 0; ii < 8; ii++) {
      int r = wave * 64 + ii * 8 + sr;
      async16(Av + (size_t)r * NNN + k0 + sg * 8, &sA[r * 64 + sp * 8]);
    }
    if (which) {
      const float* gp = S + (size_t)(x0 + xl) * NNN + k0 + ch * 16;
      float e[16];
#pragma unroll
      for (int t4 = 0; t4 < 4; t4++) {
        float4 v = ((const float4*)gp)[t4];
        e[t4 * 4 + 0] = __expf(v.x - mx);
        e[t4 * 4 + 1] = __expf(v.y - mx);
        e[t4 * 4 + 2] = __expf(v.z - mx);
        e[t4 * 4 + 3] = __expf(v.w - mx);
      }
#pragma unroll
      for (int t = 0; t < 16; t++) lsum += e[t];
      v8s pk0, pk1;
#pragma unroll
      for (int t = 0; t < 8; t++) {
        pk0[t] = (short)f2bf(e[t]);
        pk1[t] = (short)f2bf(e[t + 8]);
      }
      const int g0 = ch * 2;
      *(v8s*)&sB[xl * 64 + (g0 ^ (xl & 7)) * 8] = pk0;
      *(v8s*)&sB[xl * 64 + ((g0 + 1) ^ (xl & 7)) * 8] = pk1;
    } else {
      const float* gp = S + (size_t)(k0 + kq) * NNN + x0 + xs;
      float e[16];
#pragma unroll
      for (int t = 0; t < 16; t++)
        e[t] = __expf(gp[(size_t)t * NNN] - mx);
#pragma unroll
      for (int t = 0; t < 16; t++) lsum += e[t];
      v8s pk0, pk1;
#pragma unroll
      for (int t = 0; t < 8; t++) {
        pk0[t] = (short)f2bf(e[t]);
        pk1[t] = (short)f2bf(e[t + 8]);
      }
      const int g0 = (tid >> 6) * 2;
      *(v8s*)&sB[xs * 64 + (g0 ^ (xs & 7)) * 8] = pk0;
      *(v8s*)&sB[xs * 64 + ((g0 + 1) ^ (xs & 7)) * 8] = pk1;
    }
    __syncthreads();
#pragma unroll
    for (int s = 0; s < 2; s++) {
      const int pa = (s * 4 + q) ^ l7;
      v8s af[4], bfr[4];
#pragma unroll
      for (int i = 0; i < 4; i++)
        af[i] = *(const v8s*)&sA[(wave * 64 + i * 16 + l) * 64 + pa * 8];
#pragma unroll
      for (int j = 0; j < 4; j++)
        bfr[j] = *(const v8s*)&sB[(j * 16 + l) * 64 + pa * 8];
#pragma unroll
      for (int i = 0; i < 4; i++)
#pragma unroll
        for (int j = 0; j < 4; j++)
          acc[i][j] = __builtin_amdgcn_mfma_f32_16x16x32_bf16(af[i], bfr[j],
                                                              acc[i][j], 0, 0, 0);
    }
  }

  // L partial reduction: 4 threads contribute per x
  __syncthreads();
  lsh[tid] = lsum;
  __syncthreads();
  if (tid < 64) {
    float t;
    if (which)
      t = (lsh[tid * 4] + lsh[tid * 4 + 1]) + (lsh[tid * 4 + 2] + lsh[tid * 4 + 3]);
    else
      t = (lsh[tid] + lsh[tid + 64]) + (lsh[tid + 128] + lsh[tid + 192]);
    Lpo[x0 + tid] = t;
  }

#pragma unroll
  for (int i = 0; i < 4; i++)
#pragma unroll
    for (int j = 0; j < 4; j++)
#pragma unroll
      for (int r = 0; r < 4; r++) {
        int c = wave * 64 + i * 16 + q * 4 + r;
        int x = x0 + j * 16 + l;
        Out[(size_t)c * NNN + x] = acc[i][j][r];
      }
}

// ---- reduce 4 K-split partials + L partials, apply 1/L, write output ----
__global__ __launch_bounds__(256) void pv_reduce(
    const float* __restrict__ part, const float* __restrict__ Lp,
    float* __restrict__ outA, float* __restrict__ outB, int batch) {
  const int bi = blockIdx.x;  // 0..511
  const int which = bi >> 8;
  const int c = bi & 255;
  float* Out = (which ? outB : outA) + (size_t)batch * CC * NNN +
               (size_t)c * NNN;
  const float* p0 = part + (size_t)which * (CC * NNN) + (size_t)c * NNN;
  const float* l0 = Lp + (size_t)which * NNN;
  const size_t ps = 2 * (size_t)CC * NNN;
  const size_t ls = 2 * (size_t)NNN;
  const int t = threadIdx.x;
#pragma unroll
  for (int xi = 0; xi < 4; xi++) {
    int x = xi * 1024 + t * 4;
    float4 a0 = *(const float4*)(p0 + x);
    float4 a1 = *(const float4*)(p0 + ps + x);
    float4 a2 = *(const float4*)(p0 + 2 * ps + x);
    float4 a3 = *(const float4*)(p0 + 3 * ps + x);
    float4 q0 = *(const float4*)(l0 + x);
    float4 q1 = *(const float4*)(l0 + ls + x);
    float4 q2 = *(const float4*)(l0 + 2 * ls + x);
    float4 q3 = *(const float4*)(l0 + 3 * ls + x);
    float4 o;
    o.x = ((a0.x + a1.x) + (a2.x + a3.x)) / ((q0.x + q1.x) + (q2.x + q3.x));
    o.y = ((a0.y + a1.y) + (a2.y + a3.y)) / ((q0.y + q1.y) + (q2.y + q3.y));
    o.z = ((a0.z + a1.z) + (a2.z + a3.z)) / ((q0.z + q1.z) + (q2.z + q3.z));
    o.w = ((a0.w + a1.w) + (a2.w + a3.w)) / ((q0.w + q1.w) + (q2.w + q3.w));
    *(float4*)(Out + x) = o;
  }
}

extern "C" void kernel_launch(void* const* d_in, const int* in_sizes, int n_in,
                              void* d_out, int out_size, void* d_ws,
                              size_t ws_size, hipStream_t stream) {
  const float* a = (const float*)d_in[0];
  const float* b = (const float*)d_in[1];
  const float* W = (const float*)d_in[2];
  float* out = (float*)d_out;

  char* ws = (char*)d_ws;
  u16* Ws = (u16*)(ws);                     // 262144
  u16* aTs = (u16*)(ws + 262144);           // 16777216
  u16* bTs = (u16*)(ws + 17039360);         // 16777216
  u16* aCb = (u16*)(ws + 33816576);         // 8388608
  u16* bCb = (u16*)(ws + 42205184);         // 8388608
  u16* ats = (u16*)(ws + 50593792);         // 16777216
  u32* Mru = (u32*)(ws + 67371008);         // [4][4096] u32 = 65536
  u32* Mcu = (u32*)(ws + 67436544);         // 65536
  float* Lp = (float*)(ws + 67502080);      // 4*2*4096*4 = 131072
  float* Sbuf = (float*)(ws + 67633152);    // 67108864
  float* Ppart = (float*)(ws + 134742016);  // 33554432 -> ends ~168 MB
  // ws >= 235 MB (proven: round-4 ksplit engaged); ~168 MB needed.

  wsplit<<<dim3(256), 256, 0, stream>>>(W, Ws);
  tsplit<<<dim3(64, 4, 4), 256, 0, stream>>>(a, aTs, aCb);
  tsplit<<<dim3(64, 4, 4), 256, 0, stream>>>(b, bTs, bCb);
  gemm_tn<0><<<dim3(32, 2, 4), 256, 0, stream>>>(
      aTs, (long)NNN * 512, Ws, 0, ats, (long)NNN * 512, nullptr, nullptr,
      nullptr);
  hipMemsetAsync(Mru, 0, 131072, stream);  // all 4 batches' Mru+Mcu

  for (int p = 0; p < 4; p++) {
    const u16* atp = ats + (size_t)p * NNN * 512;
    const u16* btp = bTs + (size_t)p * NNN * 512;
    gemm_tn<1><<<dim3(32, 32, 1), 256, 0, stream>>>(
        atp, 0, btp, 0, nullptr, 0, Sbuf, Mru + p * 4096, Mcu + p * 4096);
    pv_part<<<dim3(64, 2, 4), 256, 0, stream>>>(
        aCb, bCb, Sbuf, Mru + p * 4096, Mcu + p * 4096, Ppart, Lp, p);
    pv_reduce<<<dim3(512), 256, 0, stream>>>(
        Ppart, Lp, out, out + 4194304, p);
  }
}

// Round 7
// 459.844 us; speedup vs baseline: 2.0241x; 1.0031x over previous
//
#include <hip/hip_runtime.h>
#include <stdint.h>

typedef unsigned short u16;
typedef unsigned int u32;
typedef float v4f __attribute__((ext_vector_type(4)));
typedef short v8s __attribute__((ext_vector_type(8)));

#define CC 256
#define NNN 4096

__device__ __forceinline__ u16 f2bf(float f) {
  union { float f; uint32_t u; } c; c.f = f;
  uint32_t u = c.u;
  return (u16)((u + 0x7fffu + ((u >> 16) & 1u)) >> 16);
}
__device__ __forceinline__ float bf2f(u16 h) {
  union { uint32_t u; float f; } c; c.u = ((uint32_t)h) << 16;
  return c.f;
}
// monotone float<->uint encoding for atomicMax on fp32
__device__ __forceinline__ u32 encf(float f) {
  u32 u = __float_as_uint(f);
  return (u >> 31) ? ~u : (u | 0x80000000u);
}
__device__ __forceinline__ float decf(u32 u) {
  return (u >> 31) ? __uint_as_float(u & 0x7fffffffu) : __uint_as_float(~u);
}
__device__ __forceinline__ void async16(const void* g, void* l) {
  __builtin_amdgcn_global_load_lds(
      (const __attribute__((address_space(1))) uint32_t*)g,
      (__attribute__((address_space(3))) uint32_t*)l, 16, 0, 0);
}

// ---- W [256][256] fp32 -> Ws [256][512] bf16 (hi | lo), K(c)-fast ----
__global__ __launch_bounds__(256) void wsplit(const float* __restrict__ W,
                                              u16* __restrict__ Ws) {
  const int d = blockIdx.x, c = threadIdx.x;
  float w = W[d * 256 + c];
  u16 hi = f2bf(w);
  Ws[d * 512 + c] = hi;
  Ws[d * 512 + 256 + c] = f2bf(w - bf2f(hi));
}

// ---- per batch: in [C][N] fp32 -> Ts [N][512] bf16 (hi|lo over c),
//      and Cb [C][N] bf16 (hi, straight copy) ----
__global__ __launch_bounds__(256) void tsplit(const float* __restrict__ in,
                                              u16* __restrict__ Ts,
                                              u16* __restrict__ Cb) {
  __shared__ u16 th[64][65];
  __shared__ u16 tl[64][65];
  const int bb = blockIdx.z;
  const int n0 = blockIdx.x * 64;
  const int c0 = blockIdx.y * 64;
  const int tx = threadIdx.x & 63;
  const int ty = threadIdx.x >> 6;  // 0..3
  const float* ib = in + (size_t)bb * CC * NNN;
  u16* Tb = Ts + (size_t)bb * NNN * 512;
  u16* Cbb = Cb + (size_t)bb * CC * NNN;
#pragma unroll
  for (int k = 0; k < 16; k++) {
    int r = ty + k * 4;
    float v = ib[(size_t)(c0 + r) * NNN + n0 + tx];
    u16 hi = f2bf(v);
    u16 lo = f2bf(v - bf2f(hi));
    th[r][tx] = hi;
    tl[r][tx] = lo;
    Cbb[(size_t)(c0 + r) * NNN + n0 + tx] = hi;
  }
  __syncthreads();
#pragma unroll
  for (int k = 0; k < 16; k++) {
    int r = ty + k * 4;
    Tb[(size_t)(n0 + r) * 512 + c0 + tx] = th[tx][r];
    Tb[(size_t)(n0 + r) * 512 + 256 + c0 + tx] = tl[tx][r];
  }
}

// ---- TN GEMM, logical K=768 over [hi|lo] stored operands (pitch 512).
// BK=64, XOR-swizzled LDS: LDS[r][p] = global chunk p^(r&7) (8-short chunks).
// MODE 1 tiles are XCD-clustered: linear%8 = XCD [m09]; each XCD gets an
// 8m x 16n region so its L2 working set is A 1MB + B 2MB < 4MB.
template <int MODE>
__global__ __launch_bounds__(256) void gemm_tn(
    const u16* __restrict__ A, long sAb, const u16* __restrict__ Bm, long sBb,
    u16* __restrict__ outb, long sOb, float* __restrict__ S,
    u32* __restrict__ Mru, u32* __restrict__ Mcu) {
  const int bz = blockIdx.z;
  const u16* Ab = A + (size_t)bz * sAb;
  const u16* Bb = Bm + (size_t)bz * sBb;
  int m0, n0;
  if (MODE == 0) {
    m0 = blockIdx.x * 128;
    n0 = blockIdx.y * 128;
  } else {
    const int bidl = blockIdx.x + (int)gridDim.x * blockIdx.y;  // 0..1023
    const int xcd = bidl & 7, idx = bidl >> 3;                  // idx 0..127
    const int mt = (xcd & 3) * 8 + (idx & 7);
    const int nt = (xcd >> 2) * 16 + (idx >> 3);
    m0 = mt * 128;
    n0 = nt * 128;
  }
  const int tid = threadIdx.x;
  const int wave = tid >> 6;
  const int lane = tid & 63;
  const int q = lane >> 4;
  const int l = lane & 15;
  const int l7 = l & 7;
  const int wm = (wave >> 1) * 64;
  const int wn = (wave & 1) * 64;
  const int sr = lane >> 3;  // row-in-group 0..7
  const int sp = lane & 7;   // LDS chunk position 0..7
  const int sg = sp ^ sr;    // global chunk index (swizzle)

  __shared__ alignas(16) u16 sA[128 * 64];
  __shared__ alignas(16) u16 sB[128 * 64];

  v4f zero = {0.f, 0.f, 0.f, 0.f};
  v4f acc[4][4];
#pragma unroll
  for (int i = 0; i < 4; i++)
#pragma unroll
    for (int j = 0; j < 4; j++) acc[i][j] = zero;

  for (int k0 = 0; k0 < 768; k0 += 64) {
    const int kA = k0 & 511;
    const int kB = (k0 >= 256) ? (k0 - 256) : k0;
    __syncthreads();
#pragma unroll
    for (int ii = 0; ii < 4; ii++) {
      int r = wave * 32 + ii * 8 + sr;
      async16(Ab + (size_t)(m0 + r) * 512 + kA + sg * 8,
              &sA[r * 64 + sp * 8]);
    }
#pragma unroll
    for (int ii = 0; ii < 4; ii++) {
      int r = wave * 32 + ii * 8 + sr;
      async16(Bb + (size_t)(n0 + r) * 512 + kB + sg * 8,
              &sB[r * 64 + sp * 8]);
    }
    __syncthreads();
#pragma unroll
    for (int s = 0; s < 2; s++) {
      const int pa = (s * 4 + q) ^ l7;
      v8s af[4], bfr[4];
#pragma unroll
      for (int i = 0; i < 4; i++)
        af[i] = *(const v8s*)&sA[(wm + i * 16 + l) * 64 + pa * 8];
#pragma unroll
      for (int j = 0; j < 4; j++)
        bfr[j] = *(const v8s*)&sB[(wn + j * 16 + l) * 64 + pa * 8];
#pragma unroll
      for (int i = 0; i < 4; i++)
#pragma unroll
        for (int j = 0; j < 4; j++)
          acc[i][j] = __builtin_amdgcn_mfma_f32_16x16x32_bf16(af[i], bfr[j],
                                                              acc[i][j], 0, 0, 0);
    }
  }

  if (MODE == 0) {
    u16* ob = outb + (size_t)bz * sOb;
#pragma unroll
    for (int i = 0; i < 4; i++)
#pragma unroll
      for (int j = 0; j < 4; j++)
#pragma unroll
        for (int r = 0; r < 4; r++) {
          int row = m0 + wm + i * 16 + q * 4 + r;
          int col = n0 + wn + j * 16 + l;
          float v = acc[i][j][r];
          u16 hi = f2bf(v);
          ob[(size_t)row * 512 + col] = hi;
          ob[(size_t)row * 512 + 256 + col] = f2bf(v - bf2f(hi));
        }
  } else {
#pragma unroll
    for (int i = 0; i < 4; i++)
#pragma unroll
      for (int j = 0; j < 4; j++)
#pragma unroll
        for (int r = 0; r < 4; r++) {
          int row = m0 + wm + i * 16 + q * 4 + r;  // S row n
          int col = n0 + wn + j * 16 + l;          // S col m
          S[(size_t)row * NNN + col] = acc[i][j][r];
        }
    // --- row max (over this block's 128 cols) ---
    float rm[4][4];
#pragma unroll
    for (int i = 0; i < 4; i++)
#pragma unroll
      for (int r = 0; r < 4; r++)
        rm[i][r] = fmaxf(fmaxf(acc[i][0][r], acc[i][1][r]),
                         fmaxf(acc[i][2][r], acc[i][3][r]));
#pragma unroll
    for (int off = 1; off < 16; off <<= 1)
#pragma unroll
      for (int i = 0; i < 4; i++)
#pragma unroll
        for (int r = 0; r < 4; r++)
          rm[i][r] = fmaxf(rm[i][r], __shfl_xor(rm[i][r], off));
    if (l == 0) {
#pragma unroll
      for (int i = 0; i < 4; i++)
#pragma unroll
        for (int r = 0; r < 4; r++)
          atomicMax(&Mru[m0 + wm + i * 16 + q * 4 + r], encf(rm[i][r]));
    }
    // --- col max (over this block's 128 rows) ---
    float cm[4];
#pragma unroll
    for (int j = 0; j < 4; j++) {
      float v = -3e38f;
#pragma unroll
      for (int i = 0; i < 4; i++)
#pragma unroll
        for (int r = 0; r < 4; r++) v = fmaxf(v, acc[i][j][r]);
      cm[j] = v;
    }
#pragma unroll
    for (int off = 16; off < 64; off <<= 1)
#pragma unroll
      for (int j = 0; j < 4; j++) cm[j] = fmaxf(cm[j], __shfl_xor(cm[j], off));
    if (q == 0) {
#pragma unroll
      for (int j = 0; j < 4; j++)
        atomicMax(&Mcu[n0 + wn + j * 16 + l], encf(cm[j]));
    }
  }
}

// ---- K-split PV partial with fused L accumulation. BK=64, swizzled LDS.
// XCD-clustered: xcd = linear%8 -> (which,split); all 64 x-tiles of one
// (which,split) land on one XCD so the V k-slice (512 KB) pins in its L2.
__global__ __launch_bounds__(256) void pv_part(
    const u16* __restrict__ aV, const u16* __restrict__ bV,
    const float* __restrict__ S, const u32* __restrict__ Mru,
    const u32* __restrict__ Mcu, float* __restrict__ part,
    float* __restrict__ Lp, int batch) {
  const int lin =
      blockIdx.x + 64 * (blockIdx.y + 2 * blockIdx.z);  // 0..511
  const int xcd = lin & 7;
  const int which = xcd & 1;
  const int split = xcd >> 1;
  const int x0 = (lin >> 3) * 64;
  const u16* Av = (which ? bV : aV) + (size_t)batch * (CC * NNN);
  const u32* Mst = which ? Mru : Mcu;
  float* Out = part + ((size_t)split * 2 + which) * (CC * NNN);
  float* Lpo = Lp + ((size_t)split * 2 + which) * NNN;

  const int tid = threadIdx.x;
  const int wave = tid >> 6, lane = tid & 63, q = lane >> 4, l = lane & 15;
  const int l7 = l & 7;
  const int sr = lane >> 3, sp = lane & 7, sg = sp ^ sr;
  // which=1 S-read coords: 64 x-rows x 4 chunks of 16 k
  const int xl = tid >> 2, ch = tid & 3;
  // which=0 S-read coords: 64 x-cols x 4 groups of 16 k-rows
  const int xs = tid & 63, kq = (tid >> 6) * 16;

  __shared__ alignas(16) u16 sA[256 * 64];
  __shared__ alignas(16) u16 sB[64 * 64];
  __shared__ float lsh[256];

  v4f zero = {0.f, 0.f, 0.f, 0.f};
  v4f acc[4][4];
#pragma unroll
  for (int i = 0; i < 4; i++)
#pragma unroll
    for (int j = 0; j < 4; j++) acc[i][j] = zero;

  const float mx = decf(Mst[x0 + (which ? xl : xs)]);
  float lsum = 0.f;
  const int kbeg = split * 1024;

  for (int k0 = kbeg; k0 < kbeg + 1024; k0 += 64) {
    __syncthreads();
#pragma unroll
    for (int ii = 0; ii < 8; ii++) {
      int r = wave * 64 + ii * 8 + sr;
      async16(Av + (size_t)r * NNN + k0 + sg * 8, &sA[r * 64 + sp * 8]);
    }
    if (which) {
      const float* gp = S + (size_t)(x0 + xl) * NNN + k0 + ch * 16;
      float e[16];
#pragma unroll
      for (int t4 = 0; t4 < 4; t4++) {
        float4 v = ((const float4*)gp)[t4];
        e[t4 * 4 + 0] = __expf(v.x - mx);
        e[t4 * 4 + 1] = __expf(v.y - mx);
        e[t4 * 4 + 2] = __expf(v.z - mx);
        e[t4 * 4 + 3] = __expf(v.w - mx);
      }
#pragma unroll
      for (int t = 0; t < 16; t++) lsum += e[t];
      v8s pk0, pk1;
#pragma unroll
      for (int t = 0; t < 8; t++) {
        pk0[t] = (short)f2bf(e[t]);
        pk1[t] = (short)f2bf(e[t + 8]);
      }
      const int g0 = ch * 2;
      *(v8s*)&sB[xl * 64 + (g0 ^ (xl & 7)) * 8] = pk0;
      *(v8s*)&sB[xl * 64 + ((g0 + 1) ^ (xl & 7)) * 8] = pk1;
    } else {
      const float* gp = S + (size_t)(k0 + kq) * NNN + x0 + xs;
      float e[16];
#pragma unroll
      for (int t = 0; t < 16; t++)
        e[t] = __expf(gp[(size_t)t * NNN] - mx);
#pragma unroll
      for (int t = 0; t < 16; t++) lsum += e[t];
      v8s pk0, pk1;
#pragma unroll
      for (int t = 0; t < 8; t++) {
        pk0[t] = (short)f2bf(e[t]);
        pk1[t] = (short)f2bf(e[t + 8]);
      }
      const int g0 = (tid >> 6) * 2;
      *(v8s*)&sB[xs * 64 + (g0 ^ (xs & 7)) * 8] = pk0;
      *(v8s*)&sB[xs * 64 + ((g0 + 1) ^ (xs & 7)) * 8] = pk1;
    }
    __syncthreads();
#pragma unroll
    for (int s = 0; s < 2; s++) {
      const int pa = (s * 4 + q) ^ l7;
      v8s af[4], bfr[4];
#pragma unroll
      for (int i = 0; i < 4; i++)
        af[i] = *(const v8s*)&sA[(wave * 64 + i * 16 + l) * 64 + pa * 8];
#pragma unroll
      for (int j = 0; j < 4; j++)
        bfr[j] = *(const v8s*)&sB[(j * 16 + l) * 64 + pa * 8];
#pragma unroll
      for (int i = 0; i < 4; i++)
#pragma unroll
        for (int j = 0; j < 4; j++)
          acc[i][j] = __builtin_amdgcn_mfma_f32_16x16x32_bf16(af[i], bfr[j],
                                                              acc[i][j], 0, 0, 0);
    }
  }

  // L partial reduction: 4 threads contribute per x
  __syncthreads();
  lsh[tid] = lsum;
  __syncthreads();
  if (tid < 64) {
    float t;
    if (which)
      t = (lsh[tid * 4] + lsh[tid * 4 + 1]) + (lsh[tid * 4 + 2] + lsh[tid * 4 + 3]);
    else
      t = (lsh[tid] + lsh[tid + 64]) + (lsh[tid + 128] + lsh[tid + 192]);
    Lpo[x0 + tid] = t;
  }

#pragma unroll
  for (int i = 0; i < 4; i++)
#pragma unroll
    for (int j = 0; j < 4; j++)
#pragma unroll
      for (int r = 0; r < 4; r++) {
        int c = wave * 64 + i * 16 + q * 4 + r;
        int x = x0 + j * 16 + l;
        Out[(size_t)c * NNN + x] = acc[i][j][r];
      }
}

// ---- reduce 4 K-split partials + L partials, apply 1/L, write output ----
__global__ __launch_bounds__(256) void pv_reduce(
    const float* __restrict__ part, const float* __restrict__ Lp,
    float* __restrict__ outA, float* __restrict__ outB, int batch) {
  const int bi = blockIdx.x;  // 0..511
  const int which = bi >> 8;
  const int c = bi & 255;
  float* Out = (which ? outB : outA) + (size_t)batch * CC * NNN +
               (size_t)c * NNN;
  const float* p0 = part + (size_t)which * (CC * NNN) + (size_t)c * NNN;
  const float* l0 = Lp + (size_t)which * NNN;
  const size_t ps = 2 * (size_t)CC * NNN;
  const size_t ls = 2 * (size_t)NNN;
  const int t = threadIdx.x;
#pragma unroll
  for (int xi = 0; xi < 4; xi++) {
    int x = xi * 1024 + t * 4;
    float4 a0 = *(const float4*)(p0 + x);
    float4 a1 = *(const float4*)(p0 + ps + x);
    float4 a2 = *(const float4*)(p0 + 2 * ps + x);
    float4 a3 = *(const float4*)(p0 + 3 * ps + x);
    float4 q0 = *(const float4*)(l0 + x);
    float4 q1 = *(const float4*)(l0 + ls + x);
    float4 q2 = *(const float4*)(l0 + 2 * ls + x);
    float4 q3 = *(const float4*)(l0 + 3 * ls + x);
    float4 o;
    o.x = ((a0.x + a1.x) + (a2.x + a3.x)) / ((q0.x + q1.x) + (q2.x + q3.x));
    o.y = ((a0.y + a1.y) + (a2.y + a3.y)) / ((q0.y + q1.y) + (q2.y + q3.y));
    o.z = ((a0.z + a1.z) + (a2.z + a3.z)) / ((q0.z + q1.z) + (q2.z + q3.z));
    o.w = ((a0.w + a1.w) + (a2.w + a3.w)) / ((q0.w + q1.w) + (q2.w + q3.w));
    *(float4*)(Out + x) = o;
  }
}

extern "C" void kernel_launch(void* const* d_in, const int* in_sizes, int n_in,
                              void* d_out, int out_size, void* d_ws,
                              size_t ws_size, hipStream_t stream) {
  const float* a = (const float*)d_in[0];
  const float* b = (const float*)d_in[1];
  const float* W = (const float*)d_in[2];
  float* out = (float*)d_out;

  char* ws = (char*)d_ws;
  u16* Ws = (u16*)(ws);                     // 262144
  u16* aTs = (u16*)(ws + 262144);           // 16777216
  u16* bTs = (u16*)(ws + 17039360);         // 16777216
  u16* aCb = (u16*)(ws + 33816576);         // 8388608
  u16* bCb = (u16*)(ws + 42205184);         // 8388608
  u16* ats = (u16*)(ws + 50593792);         // 16777216
  u32* Mru = (u32*)(ws + 67371008);         // [4][4096] u32 = 65536
  u32* Mcu = (u32*)(ws + 67436544);         // 65536
  float* Lp = (float*)(ws + 67502080);      // 4*2*4096*4 = 131072
  float* Sbuf = (float*)(ws + 67633152);    // 67108864
  float* Ppart = (float*)(ws + 134742016);  // 33554432 -> ends ~168 MB

  wsplit<<<dim3(256), 256, 0, stream>>>(W, Ws);
  tsplit<<<dim3(64, 4, 4), 256, 0, stream>>>(a, aTs, aCb);
  tsplit<<<dim3(64, 4, 4), 256, 0, stream>>>(b, bTs, bCb);
  gemm_tn<0><<<dim3(32, 2, 4), 256, 0, stream>>>(
      aTs, (long)NNN * 512, Ws, 0, ats, (long)NNN * 512, nullptr, nullptr,
      nullptr);
  hipMemsetAsync(Mru, 0, 131072, stream);  // all 4 batches' Mru+Mcu

  for (int p = 0; p < 4; p++) {
    const u16* atp = ats + (size_t)p * NNN * 512;
    const u16* btp = bTs + (size_t)p * NNN * 512;
    gemm_tn<1><<<dim3(32, 32, 1), 256, 0, stream>>>(
        atp, 0, btp, 0, nullptr, 0, Sbuf, Mru + p * 4096, Mcu + p * 4096);
    pv_part<<<dim3(64, 2, 4), 256, 0, stream>>>(
        aCb, bCb, Sbuf, Mru + p * 4096, Mcu + p * 4096, Ppart, Lp, p);
    pv_reduce<<<dim3(512), 256, 0, stream>>>(
        Ppart, Lp, out, out + 4194304, p);
  }
}

// Round 8
// 424.509 us; speedup vs baseline: 2.1926x; 1.0832x over previous
//
#include <hip/hip_runtime.h>
#include <stdint.h>

typedef unsigned short u16;
typedef unsigned int u32;
typedef _Float16 f16;
typedef float v4f __attribute__((ext_vector_type(4)));
typedef f16 v8h __attribute__((ext_vector_type(8)));

#define CC 256
#define NNN 4096

__device__ __forceinline__ u16 f2h(float f) {
  union { f16 h; u16 u; } c; c.h = (f16)f; return c.u;
}
// monotone float<->uint encoding for atomicMax on fp32
__device__ __forceinline__ u32 encf(float f) {
  u32 u = __float_as_uint(f);
  return (u >> 31) ? ~u : (u | 0x80000000u);
}
__device__ __forceinline__ float decf(u32 u) {
  return (u >> 31) ? __uint_as_float(u & 0x7fffffffu) : __uint_as_float(~u);
}
__device__ __forceinline__ void async16(const void* g, void* l) {
  __builtin_amdgcn_global_load_lds(
      (const __attribute__((address_space(1))) uint32_t*)g,
      (__attribute__((address_space(3))) uint32_t*)l, 16, 0, 0);
}

// ---- W [256][256] fp32 -> Ws [256][512] fp16 (hi | lo), K(c)-fast ----
__global__ __launch_bounds__(256) void wsplit(const float* __restrict__ W,
                                              u16* __restrict__ Ws) {
  const int d = blockIdx.x, c = threadIdx.x;
  float w = W[d * 256 + c];
  f16 hi = (f16)w;
  f16 lo = (f16)(w - (float)hi);
  union { f16 h; u16 u; } ch, cl; ch.h = hi; cl.h = lo;
  Ws[d * 512 + c] = ch.u;
  Ws[d * 512 + 256 + c] = cl.u;
}

// ---- per batch: in [C][N] fp32 -> T [N][256] fp16 (transposed, K-fast),
//      and Cb [C][N] fp16 (straight copy) ----
__global__ __launch_bounds__(256) void tsplit(const float* __restrict__ in,
                                              u16* __restrict__ T,
                                              u16* __restrict__ Cb) {
  __shared__ u16 th[64][65];
  const int bb = blockIdx.z;
  const int n0 = blockIdx.x * 64;
  const int c0 = blockIdx.y * 64;
  const int tx = threadIdx.x & 63;
  const int ty = threadIdx.x >> 6;  // 0..3
  const float* ib = in + (size_t)bb * CC * NNN;
  u16* Tb = T + (size_t)bb * NNN * 256;
  u16* Cbb = Cb + (size_t)bb * CC * NNN;
#pragma unroll
  for (int k = 0; k < 16; k++) {
    int r = ty + k * 4;
    float v = ib[(size_t)(c0 + r) * NNN + n0 + tx];
    u16 h = f2h(v);
    th[r][tx] = h;
    Cbb[(size_t)(c0 + r) * NNN + n0 + tx] = h;
  }
  __syncthreads();
#pragma unroll
  for (int k = 0; k < 16; k++) {
    int r = ty + k * 4;
    Tb[(size_t)(n0 + r) * 256 + c0 + tx] = th[tx][r];
  }
}

// ---- TN GEMM over fp16, logical K=512 with per-operand k-masking.
// kA = k0 & ma ; kB = k0 & mb  -> 2-term hi/lo product on one operand.
// BK=64, XOR-swizzled LDS (8-elem chunks, pos = chunk ^ (row&7)).
// MODE 0: out = fp16 hi/lo, pitch 512 (a~).
// MODE 1: out = S fp32 + row/col max atomics; tiles XCD-clustered.
template <int MODE>
__global__ __launch_bounds__(256) void gemm_tn(
    const u16* __restrict__ A, long sAb, int pa, int ma,
    const u16* __restrict__ Bm, long sBb, int pb, int mb, int ktot,
    u16* __restrict__ outb, long sOb, float* __restrict__ S,
    u32* __restrict__ Mru, u32* __restrict__ Mcu) {
  const int bz = blockIdx.z;
  const u16* Ab = A + (size_t)bz * sAb;
  const u16* Bb = Bm + (size_t)bz * sBb;
  int m0, n0;
  if (MODE == 0) {
    m0 = blockIdx.x * 128;
    n0 = blockIdx.y * 128;
  } else {
    const int bidl = blockIdx.x + (int)gridDim.x * blockIdx.y;  // 0..1023
    const int xcd = bidl & 7, idx = bidl >> 3;
    const int mt = (xcd & 3) * 8 + (idx & 7);
    const int nt = (xcd >> 2) * 16 + (idx >> 3);
    m0 = mt * 128;
    n0 = nt * 128;
  }
  const int tid = threadIdx.x;
  const int wave = tid >> 6;
  const int lane = tid & 63;
  const int q = lane >> 4;
  const int l = lane & 15;
  const int l7 = l & 7;
  const int wm = (wave >> 1) * 64;
  const int wn = (wave & 1) * 64;
  const int sr = lane >> 3;  // row-in-group 0..7
  const int sp = lane & 7;   // LDS chunk position 0..7
  const int sg = sp ^ sr;    // global chunk index (swizzle)

  __shared__ alignas(16) u16 sA[128 * 64];
  __shared__ alignas(16) u16 sB[128 * 64];

  v4f zero = {0.f, 0.f, 0.f, 0.f};
  v4f acc[4][4];
#pragma unroll
  for (int i = 0; i < 4; i++)
#pragma unroll
    for (int j = 0; j < 4; j++) acc[i][j] = zero;

  for (int k0 = 0; k0 < ktot; k0 += 64) {
    const int kA = k0 & ma;
    const int kB = k0 & mb;
    __syncthreads();
#pragma unroll
    for (int ii = 0; ii < 4; ii++) {
      int r = wave * 32 + ii * 8 + sr;
      async16(Ab + (size_t)(m0 + r) * pa + kA + sg * 8,
              &sA[r * 64 + sp * 8]);
    }
#pragma unroll
    for (int ii = 0; ii < 4; ii++) {
      int r = wave * 32 + ii * 8 + sr;
      async16(Bb + (size_t)(n0 + r) * pb + kB + sg * 8,
              &sB[r * 64 + sp * 8]);
    }
    __syncthreads();
#pragma unroll
    for (int s = 0; s < 2; s++) {
      const int pa8 = (s * 4 + q) ^ l7;
      v8h af[4], bfr[4];
#pragma unroll
      for (int i = 0; i < 4; i++)
        af[i] = *(const v8h*)&sA[(wm + i * 16 + l) * 64 + pa8 * 8];
#pragma unroll
      for (int j = 0; j < 4; j++)
        bfr[j] = *(const v8h*)&sB[(wn + j * 16 + l) * 64 + pa8 * 8];
#pragma unroll
      for (int i = 0; i < 4; i++)
#pragma unroll
        for (int j = 0; j < 4; j++)
          acc[i][j] = __builtin_amdgcn_mfma_f32_16x16x32_f16(af[i], bfr[j],
                                                             acc[i][j], 0, 0, 0);
    }
  }

  if (MODE == 0) {
    u16* ob = outb + (size_t)bz * sOb;
#pragma unroll
    for (int i = 0; i < 4; i++)
#pragma unroll
      for (int j = 0; j < 4; j++)
#pragma unroll
        for (int r = 0; r < 4; r++) {
          int row = m0 + wm + i * 16 + q * 4 + r;
          int col = n0 + wn + j * 16 + l;
          float v = acc[i][j][r];
          f16 hi = (f16)v;
          f16 lo = (f16)(v - (float)hi);
          union { f16 h; u16 u; } ch, cl; ch.h = hi; cl.h = lo;
          ob[(size_t)row * 512 + col] = ch.u;
          ob[(size_t)row * 512 + 256 + col] = cl.u;
        }
  } else {
#pragma unroll
    for (int i = 0; i < 4; i++)
#pragma unroll
      for (int j = 0; j < 4; j++)
#pragma unroll
        for (int r = 0; r < 4; r++) {
          int row = m0 + wm + i * 16 + q * 4 + r;  // S row n
          int col = n0 + wn + j * 16 + l;          // S col m
          S[(size_t)row * NNN + col] = acc[i][j][r];
        }
    // --- row max (over this block's 128 cols) ---
    float rm[4][4];
#pragma unroll
    for (int i = 0; i < 4; i++)
#pragma unroll
      for (int r = 0; r < 4; r++)
        rm[i][r] = fmaxf(fmaxf(acc[i][0][r], acc[i][1][r]),
                         fmaxf(acc[i][2][r], acc[i][3][r]));
#pragma unroll
    for (int off = 1; off < 16; off <<= 1)
#pragma unroll
      for (int i = 0; i < 4; i++)
#pragma unroll
        for (int r = 0; r < 4; r++)
          rm[i][r] = fmaxf(rm[i][r], __shfl_xor(rm[i][r], off));
    if (l == 0) {
#pragma unroll
      for (int i = 0; i < 4; i++)
#pragma unroll
        for (int r = 0; r < 4; r++)
          atomicMax(&Mru[m0 + wm + i * 16 + q * 4 + r], encf(rm[i][r]));
    }
    // --- col max (over this block's 128 rows) ---
    float cm[4];
#pragma unroll
    for (int j = 0; j < 4; j++) {
      float v = -3e38f;
#pragma unroll
      for (int i = 0; i < 4; i++)
#pragma unroll
        for (int r = 0; r < 4; r++) v = fmaxf(v, acc[i][j][r]);
      cm[j] = v;
    }
#pragma unroll
    for (int off = 16; off < 64; off <<= 1)
#pragma unroll
      for (int j = 0; j < 4; j++) cm[j] = fmaxf(cm[j], __shfl_xor(cm[j], off));
    if (q == 0) {
#pragma unroll
      for (int j = 0; j < 4; j++)
        atomicMax(&Mcu[n0 + wn + j * 16 + l], encf(cm[j]));
    }
  }
}

// ---- K-split PV partial with fused L accumulation. fp16 V/P, BK=64,
// swizzled LDS, XCD-clustered (xcd -> (which,split)).
__global__ __launch_bounds__(256) void pv_part(
    const u16* __restrict__ aV, const u16* __restrict__ bV,
    const float* __restrict__ S, const u32* __restrict__ Mru,
    const u32* __restrict__ Mcu, float* __restrict__ part,
    float* __restrict__ Lp, int batch) {
  const int lin = blockIdx.x + 64 * (blockIdx.y + 2 * blockIdx.z);  // 0..511
  const int xcd = lin & 7;
  const int which = xcd & 1;
  const int split = xcd >> 1;
  const int x0 = (lin >> 3) * 64;
  const u16* Av = (which ? bV : aV) + (size_t)batch * (CC * NNN);
  const u32* Mst = which ? Mru : Mcu;
  float* Out = part + ((size_t)split * 2 + which) * (CC * NNN);
  float* Lpo = Lp + ((size_t)split * 2 + which) * NNN;

  const int tid = threadIdx.x;
  const int wave = tid >> 6, lane = tid & 63, q = lane >> 4, l = lane & 15;
  const int l7 = l & 7;
  const int sr = lane >> 3, sp = lane & 7, sg = sp ^ sr;
  // which=1 S-read coords: 64 x-rows x 4 chunks of 16 k
  const int xl = tid >> 2, ch = tid & 3;
  // which=0 S-read coords: 64 x-cols x 4 groups of 16 k-rows
  const int xs = tid & 63, kq = (tid >> 6) * 16;

  __shared__ alignas(16) u16 sA[256 * 64];
  __shared__ alignas(16) u16 sB[64 * 64];
  __shared__ float lsh[256];

  v4f zero = {0.f, 0.f, 0.f, 0.f};
  v4f acc[4][4];
#pragma unroll
  for (int i = 0; i < 4; i++)
#pragma unroll
    for (int j = 0; j < 4; j++) acc[i][j] = zero;

  const float mx = decf(Mst[x0 + (which ? xl : xs)]);
  float lsum = 0.f;
  const int kbeg = split * 1024;

  for (int k0 = kbeg; k0 < kbeg + 1024; k0 += 64) {
    __syncthreads();
#pragma unroll
    for (int ii = 0; ii < 8; ii++) {
      int r = wave * 64 + ii * 8 + sr;
      async16(Av + (size_t)r * NNN + k0 + sg * 8, &sA[r * 64 + sp * 8]);
    }
    if (which) {
      const float* gp = S + (size_t)(x0 + xl) * NNN + k0 + ch * 16;
      float e[16];
#pragma unroll
      for (int t4 = 0; t4 < 4; t4++) {
        float4 v = ((const float4*)gp)[t4];
        e[t4 * 4 + 0] = __expf(v.x - mx);
        e[t4 * 4 + 1] = __expf(v.y - mx);
        e[t4 * 4 + 2] = __expf(v.z - mx);
        e[t4 * 4 + 3] = __expf(v.w - mx);
      }
#pragma unroll
      for (int t = 0; t < 16; t++) lsum += e[t];
      v8h pk0, pk1;
#pragma unroll
      for (int t = 0; t < 8; t++) {
        pk0[t] = (f16)e[t];
        pk1[t] = (f16)e[t + 8];
      }
      const int g0 = ch * 2;
      *(v8h*)&sB[xl * 64 + (g0 ^ (xl & 7)) * 8] = pk0;
      *(v8h*)&sB[xl * 64 + ((g0 + 1) ^ (xl & 7)) * 8] = pk1;
    } else {
      const float* gp = S + (size_t)(k0 + kq) * NNN + x0 + xs;
      float e[16];
#pragma unroll
      for (int t = 0; t < 16; t++)
        e[t] = __expf(gp[(size_t)t * NNN] - mx);
#pragma unroll
      for (int t = 0; t < 16; t++) lsum += e[t];
      v8h pk0, pk1;
#pragma unroll
      for (int t = 0; t < 8; t++) {
        pk0[t] = (f16)e[t];
        pk1[t] = (f16)e[t + 8];
      }
      const int g0 = (tid >> 6) * 2;
      *(v8h*)&sB[xs * 64 + (g0 ^ (xs & 7)) * 8] = pk0;
      *(v8h*)&sB[xs * 64 + ((g0 + 1) ^ (xs & 7)) * 8] = pk1;
    }
    __syncthreads();
#pragma unroll
    for (int s = 0; s < 2; s++) {
      const int pa8 = (s * 4 + q) ^ l7;
      v8h af[4], bfr[4];
#pragma unroll
      for (int i = 0; i < 4; i++)
        af[i] = *(const v8h*)&sA[(wave * 64 + i * 16 + l) * 64 + pa8 * 8];
#pragma unroll
      for (int j = 0; j < 4; j++)
        bfr[j] = *(const v8h*)&sB[(j * 16 + l) * 64 + pa8 * 8];
#pragma unroll
      for (int i = 0; i < 4; i++)
#pragma unroll
        for (int j = 0; j < 4; j++)
          acc[i][j] = __builtin_amdgcn_mfma_f32_16x16x32_f16(af[i], bfr[j],
                                                             acc[i][j], 0, 0, 0);
    }
  }

  // L partial reduction: 4 threads contribute per x
  __syncthreads();
  lsh[tid] = lsum;
  __syncthreads();
  if (tid < 64) {
    float t;
    if (which)
      t = (lsh[tid * 4] + lsh[tid * 4 + 1]) + (lsh[tid * 4 + 2] + lsh[tid * 4 + 3]);
    else
      t = (lsh[tid] + lsh[tid + 64]) + (lsh[tid + 128] + lsh[tid + 192]);
    Lpo[x0 + tid] = t;
  }

#pragma unroll
  for (int i = 0; i < 4; i++)
#pragma unroll
    for (int j = 0; j < 4; j++)
#pragma unroll
      for (int r = 0; r < 4; r++) {
        int c = wave * 64 + i * 16 + q * 4 + r;
        int x = x0 + j * 16 + l;
        Out[(size_t)c * NNN + x] = acc[i][j][r];
      }
}

// ---- reduce 4 K-split partials + L partials, apply 1/L, write output ----
__global__ __launch_bounds__(256) void pv_reduce(
    const float* __restrict__ part, const float* __restrict__ Lp,
    float* __restrict__ outA, float* __restrict__ outB, int batch) {
  const int bi = blockIdx.x;  // 0..511
  const int which = bi >> 8;
  const int c = bi & 255;
  float* Out = (which ? outB : outA) + (size_t)batch * CC * NNN +
               (size_t)c * NNN;
  const float* p0 = part + (size_t)which * (CC * NNN) + (size_t)c * NNN;
  const float* l0 = Lp + (size_t)which * NNN;
  const size_t ps = 2 * (size_t)CC * NNN;
  const size_t ls = 2 * (size_t)NNN;
  const int t = threadIdx.x;
#pragma unroll
  for (int xi = 0; xi < 4; xi++) {
    int x = xi * 1024 + t * 4;
    float4 a0 = *(const float4*)(p0 + x);
    float4 a1 = *(const float4*)(p0 + ps + x);
    float4 a2 = *(const float4*)(p0 + 2 * ps + x);
    float4 a3 = *(const float4*)(p0 + 3 * ps + x);
    float4 q0 = *(const float4*)(l0 + x);
    float4 q1 = *(const float4*)(l0 + ls + x);
    float4 q2 = *(const float4*)(l0 + 2 * ls + x);
    float4 q3 = *(const float4*)(l0 + 3 * ls + x);
    float4 o;
    o.x = ((a0.x + a1.x) + (a2.x + a3.x)) / ((q0.x + q1.x) + (q2.x + q3.x));
    o.y = ((a0.y + a1.y) + (a2.y + a3.y)) / ((q0.y + q1.y) + (q2.y + q3.y));
    o.z = ((a0.z + a1.z) + (a2.z + a3.z)) / ((q0.z + q1.z) + (q2.z + q3.z));
    o.w = ((a0.w + a1.w) + (a2.w + a3.w)) / ((q0.w + q1.w) + (q2.w + q3.w));
    *(float4*)(Out + x) = o;
  }
}

extern "C" void kernel_launch(void* const* d_in, const int* in_sizes, int n_in,
                              void* d_out, int out_size, void* d_ws,
                              size_t ws_size, hipStream_t stream) {
  const float* a = (const float*)d_in[0];
  const float* b = (const float*)d_in[1];
  const float* W = (const float*)d_in[2];
  float* out = (float*)d_out;

  char* ws = (char*)d_ws;
  u16* Ws = (u16*)(ws);                     // 262144
  u16* aT = (u16*)(ws + 262144);            // 4*4096*256*2 = 8388608
  u16* bT = (u16*)(ws + 8650752);           // 8388608
  u16* aCb = (u16*)(ws + 17039360);         // 8388608
  u16* bCb = (u16*)(ws + 25427968);         // 8388608
  u16* ats = (u16*)(ws + 33816576);         // 4*4096*512*2 = 16777216
  u32* Mru = (u32*)(ws + 50593792);         // [4][4096] u32 = 65536
  u32* Mcu = (u32*)(ws + 50659328);         // 65536
  float* Lp = (float*)(ws + 50724864);      // 131072
  float* Sbuf = (float*)(ws + 50855936);    // 67108864
  float* Ppart = (float*)(ws + 117964800);  // 33554432 -> ends ~151.5 MB

  wsplit<<<dim3(256), 256, 0, stream>>>(W, Ws);
  tsplit<<<dim3(64, 4, 4), 256, 0, stream>>>(a, aT, aCb);
  tsplit<<<dim3(64, 4, 4), 256, 0, stream>>>(b, bT, bCb);
  // a~[n][d] = sum_c aT[n][c] * (Whi+Wlo)[d][c], K=512, out fp16 hi|lo
  gemm_tn<0><<<dim3(32, 2, 4), 256, 0, stream>>>(
      aT, (long)NNN * 256, 256, 255, Ws, 0, 512, 511, 512,
      ats, (long)NNN * 512, nullptr, nullptr, nullptr);
  hipMemsetAsync(Mru, 0, 131072, stream);  // all 4 batches' Mru+Mcu

  for (int p = 0; p < 4; p++) {
    const u16* atp = ats + (size_t)p * NNN * 512;
    const u16* btp = bT + (size_t)p * NNN * 256;
    // S[n][m] = sum_d (ahi+alo)[n][d] * b[m][d], K=512
    gemm_tn<1><<<dim3(32, 32, 1), 256, 0, stream>>>(
        atp, 0, 512, 511, btp, 0, 256, 255, 512,
        nullptr, 0, Sbuf, Mru + p * 4096, Mcu + p * 4096);
    pv_part<<<dim3(64, 2, 4), 256, 0, stream>>>(
        aCb, bCb, Sbuf, Mru + p * 4096, Mcu + p * 4096, Ppart, Lp, p);
    pv_reduce<<<dim3(512), 256, 0, stream>>>(
        Ppart, Lp, out, out + 4194304, p);
  }
}